// Round 6
// baseline (1383.244 us; speedup 1.0000x reference)
//
#include <hip/hip_runtime.h>
#include <hip/hip_bf16.h>
#include <math.h>

namespace {

constexpr int C_DIM  = 128;
constexpr int B_SZ   = 256;
constexpr int NP_OFF = 32768;         // np-graph node-id offset
constexpr int N_TOT  = 32896;         // 32768 + 128 combined rows
constexpr int E_P    = 524288;
constexpr int E_NP   = 2048;
constexpr int E_TOT  = E_P + E_NP;
constexpr int WALK   = 7;
constexpr int NTR    = 257;           // 256 p-block traces + 1 np trace
constexpr int ELLW   = 64;            // padded edge-list width (incl self loop)
constexpr int ELL_TOT = N_TOT * ELLW; // 2,105,344 entries
constexpr int PCH    = 64;            // channels per plane (2 planes)

// Algebra: H_t = A^t H0 W^t + sum_{k<t} (A^k 1)(b^T W^k); only traces needed:
//   trace_t[b] = <G_t[b-block rows], (W^t)^T>_F + bias-path terms,
// G_t = A^t H0 propagated sparsely. Bias path is exact but skipped when b==0.
//
// Gather-latency fix: aggregation is channel-independent, so G is stored as
// TWO column planes of 64 channels (4.21 MB each ~= one XCD's 4 MiB L2).
// Each walk step runs two passes; within a pass all gathers touch only one
// plane -> per-XCD L2-resident, ~200cy latency instead of ~450+ (LLC).
// ELL metadata is nt-loaded and Gout is nt-stored to avoid evicting the plane.
// (nt builtins need scalar types: use unsigned long long, not uint2.)

__device__ __forceinline__ float bflo(unsigned int w) { return __uint_as_float(w << 16); }
__device__ __forceinline__ float bfhi(unsigned int w) { return __uint_as_float(w & 0xffff0000u); }

// ---------------- precompute ----------------

__global__ void init_kernel(int* __restrict__ cnt, float* __restrict__ trG,
                            float* __restrict__ ctr, float* __restrict__ U0,
                            float* __restrict__ c0, int* __restrict__ bflag,
                            uint2* __restrict__ ell) {
  int i = blockIdx.x * blockDim.x + threadIdx.x;
  if (i < ELL_TOT) ell[i] = make_uint2(0u, 0u);
  if (i < N_TOT) { cnt[i] = 0; c0[i] = 1.0f; }
  if (i < WALK * NTR) { trG[i] = 0.0f; ctr[i] = 0.0f; }
  if (i < C_DIM * C_DIM) U0[i] = ((i >> 7) == (i & 127)) ? 1.0f : 0.0f;  // U_0 = I
  if (i == 0) *bflag = 0;
}

// NOTE: harness delivers integer inputs as int32
__global__ void count_kernel(const int* __restrict__ ei_p,
                             const int* __restrict__ ei_np,
                             int* __restrict__ cnt) {
  int e = blockIdx.x * blockDim.x + threadIdx.x;
  if (e < E_P) {
    int d = ei_p[E_P + e];
    atomicAdd(&cnt[d], 1);
  } else if (e < E_TOT) {
    int i = e - E_P;
    int d = ei_np[E_NP + i] + NP_OFF;
    atomicAdd(&cnt[d], 1);
  }
}

__global__ void dinv_kernel(const int* __restrict__ cnt, float* __restrict__ dinv,
                            int* __restrict__ fill, int* __restrict__ nrE,
                            uint2* __restrict__ ell) {
  int i = blockIdx.x * blockDim.x + threadIdx.x;
  if (i < N_TOT) {
    float di = rsqrtf((float)cnt[i] + 1.0f);  // +1 self loop
    dinv[i] = di;
    fill[i] = 0;
    int de = cnt[i] + 1;                       // edges incl self
    nrE[i] = (de + 3) >> 2;                    // rounds of 4 edges
    // self loop at logical slot 0 == physical slot 0
    ell[(size_t)i * ELLW] = make_uint2(__float_as_uint(di * di), (unsigned)i);
  }
}

__global__ void fill_kernel(const int* __restrict__ ei_p,
                            const int* __restrict__ ei_np,
                            int* __restrict__ fill,
                            const float* __restrict__ dinv,
                            uint2* __restrict__ ell) {
  int e = blockIdx.x * blockDim.x + threadIdx.x;
  int s, d;
  if (e < E_P) {
    s = ei_p[e];
    d = ei_p[E_P + e];
  } else if (e < E_TOT) {
    int i = e - E_P;
    s = ei_np[i] + NP_OFF;
    d = ei_np[E_NP + i] + NP_OFF;
  } else {
    return;
  }
  int k = 1 + atomicAdd(&fill[d], 1);          // logical slot (0 = self)
  if (k < ELLW) {
    int pos = ((k & 3) << 4) + (k >> 2);       // bank-striped physical slot
    ell[(size_t)d * ELLW + pos] =
        make_uint2(__float_as_uint(dinv[s] * dinv[d]), (unsigned)s);
  }
}

// G0 planes = round_bf16([x_p ; x_np]); thread handles 8 floats -> 16B store
__global__ void concat_kernel(const float* __restrict__ x_p,
                              const float* __restrict__ x_np,
                              __hip_bfloat16* __restrict__ Glo,
                              __hip_bfloat16* __restrict__ Ghi) {
  int i = blockIdx.x * blockDim.x + threadIdx.x;  // 8-elem chunk index
  const int NP8 = NP_OFF * C_DIM / 8;
  const int NT8 = N_TOT * C_DIM / 8;
  if (i >= NT8) return;
  const float* src = (i < NP8) ? (x_p + (size_t)i * 8)
                               : (x_np + (size_t)(i - NP8) * 8);
  union { __hip_bfloat16 h[8]; uint4 u; } pk;
#pragma unroll
  for (int j = 0; j < 8; ++j) pk.h[j] = __float2bfloat16(src[j]);
  const int node = i >> 4;          // 16 chunks per 128-channel row
  const int ch0  = (i & 15) * 8;    // 0..120, chunk never straddles planes
  __hip_bfloat16* plane = (ch0 < PCH) ? Glo : Ghi;
  ((uint4*)plane)[(size_t)node * 8 + ((ch0 & (PCH - 1)) >> 3)] = pk.u;
}

// ---------------- tiny per-step dense precompute ----------------
// Unew = Uprev @ W (fp32 exact), VtNew = Unew^T, dnew = (st==0 ? b : dprev @ W).
__global__ __launch_bounds__(128) void wpow_kernel(
    const float* __restrict__ W, const float* __restrict__ Uprev,
    float* __restrict__ Unew, float* __restrict__ VtNew,
    const float* __restrict__ dprev, float* __restrict__ dnew,
    const float* __restrict__ bg, int* __restrict__ bflag, int st) {
  __shared__ float urow[C_DIM];
  const int i = blockIdx.x;   // output row
  const int j = threadIdx.x;  // output col
  urow[j] = Uprev[i * C_DIM + j];
  __syncthreads();
  float s = 0.0f;
  for (int k = 0; k < C_DIM; ++k) s += urow[k] * W[k * C_DIM + j];
  Unew[i * C_DIM + j] = s;
  VtNew[j * C_DIM + i] = s;
  if (i == 0) {
    if (st == 0) {
      dnew[j] = bg[j];
      if (bg[j] != 0.0f) *bflag = 1;  // benchmark bias is 0 -> c-path skipped
    } else {
      float t = 0.0f;
      for (int k = 0; k < C_DIM; ++k) t += dprev[k] * W[k * C_DIM + j];
      dnew[j] = t;
    }
  }
}

// ---------------- fused walk step, one 64-channel plane per pass ----------------
// quarter-per-node; 16 nodes per 256-thread block. Lane gathers 8B (4 channels).
__global__ __launch_bounds__(256) void step_kernel(
    const __hip_bfloat16* __restrict__ Gin,   // plane `pl` of G_t
    __hip_bfloat16* __restrict__ Gout,        // plane `pl` of G_{t+1}
    const uint2* __restrict__ ell,
    const int* __restrict__ nrE,
    const float* __restrict__ cin,
    float* __restrict__ cout,
    const float* __restrict__ Vt,    // (W^{st+1})^T, row-major [128][128]
    const float* __restrict__ dvec,  // d_st = b^T W^st
    float* __restrict__ trG,
    float* __restrict__ ctr,
    const int* __restrict__ bflag,
    int st, int notlast, int pl) {
  const int lane = threadIdx.x & 63;
  const int wv   = threadIdx.x >> 6;
  const int q    = lane >> 4;   // quarter = node sub-index
  const int c8   = lane & 15;   // 4-channel group within plane row
  const int node = (blockIdx.x * 4 + wv) * 4 + q;   // N_TOT = 16*2056 exact

  const unsigned long long* eb64 =
      (const unsigned long long*)(ell + (size_t)node * ELLW);
  // 4 independent coalesced metadata loads (nt: don't pollute L2 plane)
  unsigned long long wA = __builtin_nontemporal_load(&eb64[c8]);
  unsigned long long wB = __builtin_nontemporal_load(&eb64[16 + c8]);
  unsigned long long wC = __builtin_nontemporal_load(&eb64[32 + c8]);
  unsigned long long wD = __builtin_nontemporal_load(&eb64[48 + c8]);
  uint2 mA = make_uint2((unsigned)wA, (unsigned)(wA >> 32));
  uint2 mB = make_uint2((unsigned)wB, (unsigned)(wB >> 32));
  uint2 mC = make_uint2((unsigned)wC, (unsigned)(wC >> 32));
  uint2 mD = make_uint2((unsigned)wD, (unsigned)(wD >> 32));
  const int nrq = nrE[node];
  const int qb  = q << 4;
  const uint2* __restrict__ G8 = (const uint2*)Gin;  // 16 uint2 per plane row

  float acc[4];
#pragma unroll
  for (int i = 0; i < 4; ++i) acc[i] = 0.0f;

#pragma unroll 2
  for (int r = 0; r < nrq; ++r) {
    const int sl = qb + r;   // source lane inside this quarter
    unsigned n0 = (unsigned)__shfl((int)mA.x, sl);
    unsigned s0 = (unsigned)__shfl((int)mA.y, sl);
    unsigned n1 = (unsigned)__shfl((int)mB.x, sl);
    unsigned s1 = (unsigned)__shfl((int)mB.y, sl);
    unsigned n2 = (unsigned)__shfl((int)mC.x, sl);
    unsigned s2 = (unsigned)__shfl((int)mC.y, sl);
    unsigned n3 = (unsigned)__shfl((int)mD.x, sl);
    unsigned s3 = (unsigned)__shfl((int)mD.y, sl);
    // 4 independent 8B row-gathers in flight (L2-resident plane)
    uint2 g0 = G8[(size_t)s0 * 16 + c8];
    uint2 g1 = G8[(size_t)s1 * 16 + c8];
    uint2 g2 = G8[(size_t)s2 * 16 + c8];
    uint2 g3 = G8[(size_t)s3 * 16 + c8];
    const float f0 = __uint_as_float(n0);
    const float f1 = __uint_as_float(n1);
    const float f2 = __uint_as_float(n2);
    const float f3 = __uint_as_float(n3);
    acc[0] += f0 * bflo(g0.x) + f1 * bflo(g1.x) + f2 * bflo(g2.x) + f3 * bflo(g3.x);
    acc[1] += f0 * bfhi(g0.x) + f1 * bfhi(g1.x) + f2 * bfhi(g2.x) + f3 * bfhi(g3.x);
    acc[2] += f0 * bflo(g0.y) + f1 * bflo(g1.y) + f2 * bflo(g2.y) + f3 * bflo(g3.y);
    acc[3] += f0 * bfhi(g0.y) + f1 * bfhi(g1.y) + f2 * bfhi(g2.y) + f3 * bfhi(g3.y);
  }

  if (notlast) {
    union { __hip_bfloat16 h[4]; unsigned long long u; } pk;
#pragma unroll
    for (int i = 0; i < 4; ++i) pk.h[i] = __float2bfloat16(acc[i]);
    // nt store: stream Gout, don't evict the resident Gin plane
    __builtin_nontemporal_store(
        pk.u, &((unsigned long long*)Gout)[(size_t)node * 16 + c8]);
  }

  // partial trace: this plane's 64-channel slice of dot(G_new[node], Vt[node&127])
  const int col = node & 127;
  const float4 v = *(const float4*)(Vt + col * C_DIM + pl * PCH + c8 * 4);
  float pd = acc[0] * v.x + acc[1] * v.y + acc[2] * v.z + acc[3] * v.w;
  pd += __shfl_xor(pd, 1);
  pd += __shfl_xor(pd, 2);
  pd += __shfl_xor(pd, 4);
  pd += __shfl_xor(pd, 8);

  const int bnz = *bflag;
  if (c8 == 0) {
    atomicAdd(&trG[st * NTR + (node >> 7)], pd);
    if (bnz && pl == 0) {  // exact bias path once per step (unused when b==0)
      const uint2* eb = ell + (size_t)node * ELLW;
      float cself = cin[node];
      float cnew = 0.0f;
      for (int p2 = 0; p2 < ELLW; ++p2) {
        uint2 e2 = eb[p2];
        cnew += __uint_as_float(e2.x) * cin[e2.y];  // slot0 gives dd*cself
      }
      if (notlast) cout[node] = cnew;
      atomicAdd(&ctr[st * NTR + (node >> 7)], cself * dvec[col]);
    }
  }
}

// ---------------- epilogue ----------------
// trace_t = trG[t] + prefix_sum_{k<=t} ctr[k]  (bias terms accumulate over k)
__global__ __launch_bounds__(256) void final_kernel(const float* __restrict__ trG,
                                                    const float* __restrict__ ctr,
                                                    const float* __restrict__ y,
                                                    const float* __restrict__ W1,
                                                    const float* __restrict__ b1,
                                                    const float* __restrict__ W2,
                                                    const float* __restrict__ b2,
                                                    float* __restrict__ out) {
  __shared__ float sm[B_SZ];
  const int b = threadIdx.x;
  const float sgn = (y[b] - 0.5f) * 2.0f;
  float runb = 0.0f, runn = 0.0f;
  float vals[WALK];
#pragma unroll
  for (int t = 0; t < WALK; ++t) {
    runb += ctr[t * NTR + b];
    runn += ctr[t * NTR + 256];
    vals[t] = ((trG[t * NTR + b] + runb) - (trG[t * NTR + 256] + runn)) * sgn;
  }

  for (int t = 0; t < WALK; ++t) {
    sm[b] = vals[t];
    __syncthreads();
    for (int off = 128; off >= 1; off >>= 1) {
      if (b < off) sm[b] += sm[b + off];
      __syncthreads();
    }
    float mean = sm[0] * (1.0f / 256.0f);
    __syncthreads();
    float d = vals[t] - mean;
    sm[b] = d * d;
    __syncthreads();
    for (int off = 128; off >= 1; off >>= 1) {
      if (b < off) sm[b] += sm[b + off];
      __syncthreads();
    }
    float stdv = sqrtf(sm[0] * (1.0f / 255.0f));  // ddof=1
    __syncthreads();
    vals[t] = d / stdv;
  }

  float o = b2[0];
#pragma unroll
  for (int j = 0; j < 15; ++j) {
    float a = b1[j];
#pragma unroll
    for (int t = 0; t < WALK; ++t) a += vals[t] * W1[t * 15 + j];
    o += fmaxf(a, 0.0f) * W2[j];
  }
  out[b] = 1.0f / (1.0f + expf(-o));
}

}  // namespace

extern "C" void kernel_launch(void* const* d_in, const int* in_sizes, int n_in,
                              void* d_out, int out_size, void* d_ws, size_t ws_size,
                              hipStream_t stream) {
  const float* x_p   = (const float*)d_in[0];
  const float* x_np  = (const float*)d_in[1];
  const float* y     = (const float*)d_in[2];
  const int* ei_p    = (const int*)d_in[3];   // int inputs arrive as int32
  const int* ei_np   = (const int*)d_in[4];
  const float* W_gcn = (const float*)d_in[5];
  const float* b_gcn = (const float*)d_in[6];
  const float* W1    = (const float*)d_in[7];
  const float* b1    = (const float*)d_in[8];
  const float* W2    = (const float*)d_in[9];
  const float* b2    = (const float*)d_in[10];
  float* out         = (float*)d_out;

  char* p = (char*)d_ws;
  auto alloc = [&](size_t bytes) -> void* {
    void* r = (void*)p;
    p += (bytes + 255) & ~(size_t)255;
    return r;
  };
  const size_t PLANE_B = (size_t)N_TOT * PCH * 2;  // 4.21 MB per plane
  __hip_bfloat16* GaLo = (__hip_bfloat16*)alloc(PLANE_B);  // G ping, ch 0-63
  __hip_bfloat16* GaHi = (__hip_bfloat16*)alloc(PLANE_B);  // G ping, ch 64-127
  __hip_bfloat16* GbLo = (__hip_bfloat16*)alloc(PLANE_B);  // G pong, ch 0-63
  __hip_bfloat16* GbHi = (__hip_bfloat16*)alloc(PLANE_B);  // G pong, ch 64-127
  uint2* ell      = (uint2*)alloc((size_t)ELL_TOT * 8);          // padded edge list
  int*   nrE      = (int*)alloc((size_t)N_TOT * 4);              // rounds per node
  float* dinv     = (float*)alloc((size_t)N_TOT * 4);
  int*   cnt      = (int*)alloc((size_t)N_TOT * 4);
  int*   fill     = (int*)alloc((size_t)N_TOT * 4);
  float* ca       = (float*)alloc((size_t)N_TOT * 4);            // c ping
  float* cb       = (float*)alloc((size_t)N_TOT * 4);            // c pong
  float* Ua       = (float*)alloc((size_t)C_DIM * C_DIM * 4);    // W^t ping
  float* Ub       = (float*)alloc((size_t)C_DIM * C_DIM * 4);    // W^t pong
  float* Vt       = (float*)alloc((size_t)C_DIM * C_DIM * 4);    // (W^t)^T
  float* da       = (float*)alloc((size_t)C_DIM * 4);            // d ping
  float* db       = (float*)alloc((size_t)C_DIM * 4);            // d pong
  float* trG      = (float*)alloc((size_t)WALK * NTR * 4);
  float* ctr      = (float*)alloc((size_t)WALK * NTR * 4);
  int*   bflag    = (int*)alloc(4);

  // --- precompute ---
  init_kernel<<<(ELL_TOT + 255) / 256, 256, 0, stream>>>(cnt, trG, ctr, Ua, ca,
                                                         bflag, ell);
  count_kernel<<<(E_TOT + 255) / 256, 256, 0, stream>>>(ei_p, ei_np, cnt);
  dinv_kernel<<<(N_TOT + 255) / 256, 256, 0, stream>>>(cnt, dinv, fill, nrE, ell);
  fill_kernel<<<(E_TOT + 255) / 256, 256, 0, stream>>>(ei_p, ei_np, fill, dinv, ell);
  {
    const int NT8 = N_TOT * C_DIM / 8;
    concat_kernel<<<(NT8 + 255) / 256, 256, 0, stream>>>(x_p, x_np, GaLo, GaHi);
  }

  // --- 7 walk steps: tiny W-power + two L2-resident plane passes ---
  __hip_bfloat16 *GcLo = GaLo, *GcHi = GaHi, *GnLo = GbLo, *GnHi = GbHi;
  float *Ucur = Ua, *Unext = Ub;
  float *ccur = ca, *cnext = cb;
  float *dcur = da, *dnext = db;
  for (int st = 0; st < WALK; ++st) {
    wpow_kernel<<<C_DIM, C_DIM, 0, stream>>>(W_gcn, Ucur, Unext, Vt, dcur, dnext,
                                             b_gcn, bflag, st);
    const int notlast = (st < WALK - 1) ? 1 : 0;
    step_kernel<<<N_TOT / 16, 256, 0, stream>>>(GcLo, GnLo, ell, nrE,
                                                ccur, cnext, Vt, dnext,
                                                trG, ctr, bflag, st, notlast, 0);
    step_kernel<<<N_TOT / 16, 256, 0, stream>>>(GcHi, GnHi, ell, nrE,
                                                ccur, cnext, Vt, dnext,
                                                trG, ctr, bflag, st, notlast, 1);
    { __hip_bfloat16* t = GcLo; GcLo = GnLo; GnLo = t; }
    { __hip_bfloat16* t = GcHi; GcHi = GnHi; GnHi = t; }
    { float* t = Ucur; Ucur = Unext; Unext = t; }
    { float* t = ccur; ccur = cnext; cnext = t; }
    { float* t = dcur; dcur = dnext; dnext = t; }
  }

  // --- standardize + MLP + sigmoid ---
  final_kernel<<<1, B_SZ, 0, stream>>>(trG, ctr, y, W1, b1, W2, b2, out);
}

// Round 7
// 1041.379 us; speedup vs baseline: 1.3283x; 1.3283x over previous
//
#include <hip/hip_runtime.h>
#include <hip/hip_bf16.h>
#include <math.h>

namespace {

constexpr int C_DIM  = 128;
constexpr int B_SZ   = 256;
constexpr int NP_OFF = 32768;         // np-graph node-id offset
constexpr int N_TOT  = 32896;         // 32768 + 128 combined rows
constexpr int E_P    = 524288;
constexpr int E_NP   = 2048;
constexpr int E_TOT  = E_P + E_NP;
constexpr int WALK   = 7;
constexpr int NTR    = 257;           // 256 p-block traces + 1 np trace
constexpr int ELLW   = 64;            // padded edge-list width (incl self loop)

// Algebra: H_t = A^t H0 W^t + sum_{k<t} (A^k 1)(b^T W^k); only traces needed:
//   trace_t[b] = <G_t[b-block rows], (W^t)^T>_F + bias-path terms,
// G_t = A^t H0 propagated sparsely. Bias path exact, skipped when b==0.
//
// Gather experiment (R7): all prior kernels issued ADDRESS-DIVERGENT gathers
// (one wave instruction touching 4 different rows) and pinned at ~6.2 random
// rows/cy chip-wide regardless of row size. This version issues fully
// CONVERGED gathers: wave-per-node, per edge all 64 lanes read one dword of
// the SAME 256B row. If the wall was divergent-instruction handling at the
// TA/L1, steps collapse to ~15us; if it's a downstream per-row chokepoint,
// steps stay ~90us and the scatter roofline is established.

__device__ __forceinline__ float bflo(unsigned int w) { return __uint_as_float(w << 16); }
__device__ __forceinline__ float bfhi(unsigned int w) { return __uint_as_float(w & 0xffff0000u); }

// ---------------- precompute ----------------

__global__ void init_kernel(int* __restrict__ cnt, float* __restrict__ trG,
                            float* __restrict__ ctr, float* __restrict__ U0,
                            float* __restrict__ c0, int* __restrict__ bflag) {
  int i = blockIdx.x * blockDim.x + threadIdx.x;
  if (i < N_TOT) { cnt[i] = 0; c0[i] = 1.0f; }
  if (i < WALK * NTR) { trG[i] = 0.0f; ctr[i] = 0.0f; }
  if (i < C_DIM * C_DIM) U0[i] = ((i >> 7) == (i & 127)) ? 1.0f : 0.0f;  // U_0 = I
  if (i == 0) *bflag = 0;
}

// NOTE: harness delivers integer inputs as int32
__global__ void count_kernel(const int* __restrict__ ei_p,
                             const int* __restrict__ ei_np,
                             int* __restrict__ cnt) {
  int e = blockIdx.x * blockDim.x + threadIdx.x;
  if (e < E_P) {
    int d = ei_p[E_P + e];
    atomicAdd(&cnt[d], 1);
  } else if (e < E_TOT) {
    int i = e - E_P;
    int d = ei_np[E_NP + i] + NP_OFF;
    atomicAdd(&cnt[d], 1);
  }
}

__global__ void dinv_kernel(const int* __restrict__ cnt, float* __restrict__ dinv,
                            int* __restrict__ fill, int* __restrict__ degE,
                            uint2* __restrict__ ell) {
  int i = blockIdx.x * blockDim.x + threadIdx.x;
  if (i < N_TOT) {
    float di = rsqrtf((float)cnt[i] + 1.0f);  // +1 self loop
    dinv[i] = di;
    fill[i] = 0;
    degE[i] = min(cnt[i] + 1, ELLW);           // slots used (incl self)
    // self loop at slot 0; slots >= degE are never read -> no ELL memset
    ell[(size_t)i * ELLW] = make_uint2(__float_as_uint(di * di), (unsigned)i);
  }
}

__global__ void fill_kernel(const int* __restrict__ ei_p,
                            const int* __restrict__ ei_np,
                            int* __restrict__ fill,
                            const float* __restrict__ dinv,
                            uint2* __restrict__ ell) {
  int e = blockIdx.x * blockDim.x + threadIdx.x;
  int s, d;
  if (e < E_P) {
    s = ei_p[e];
    d = ei_p[E_P + e];
  } else if (e < E_TOT) {
    int i = e - E_P;
    s = ei_np[i] + NP_OFF;
    d = ei_np[E_NP + i] + NP_OFF;
  } else {
    return;
  }
  int k = 1 + atomicAdd(&fill[d], 1);          // slot (0 = self)
  if (k < ELLW) {
    ell[(size_t)d * ELLW + k] =
        make_uint2(__float_as_uint(dinv[s] * dinv[d]), (unsigned)s);
  }
}

// G0 = round_bf16([x_p ; x_np]); thread handles 8 floats -> one 16B bf16 store
__global__ void concat_kernel(const float* __restrict__ x_p,
                              const float* __restrict__ x_np,
                              __hip_bfloat16* __restrict__ hb) {
  int i = blockIdx.x * blockDim.x + threadIdx.x;  // 8-elem chunk index
  const int NP8 = NP_OFF * C_DIM / 8;
  const int NT8 = N_TOT * C_DIM / 8;
  if (i >= NT8) return;
  const float* src = (i < NP8) ? (x_p + (size_t)i * 8)
                               : (x_np + (size_t)(i - NP8) * 8);
  union { __hip_bfloat16 h[8]; uint4 u; } pk;
#pragma unroll
  for (int j = 0; j < 8; ++j) pk.h[j] = __float2bfloat16(src[j]);
  ((uint4*)hb)[i] = pk.u;
}

// ---------------- tiny per-step dense precompute ----------------
// Unew = Uprev @ W (fp32 exact), VtNew = Unew^T, dnew = (st==0 ? b : dprev @ W).
__global__ __launch_bounds__(128) void wpow_kernel(
    const float* __restrict__ W, const float* __restrict__ Uprev,
    float* __restrict__ Unew, float* __restrict__ VtNew,
    const float* __restrict__ dprev, float* __restrict__ dnew,
    const float* __restrict__ bg, int* __restrict__ bflag, int st) {
  __shared__ float urow[C_DIM];
  const int i = blockIdx.x;   // output row
  const int j = threadIdx.x;  // output col
  urow[j] = Uprev[i * C_DIM + j];
  __syncthreads();
  float s = 0.0f;
  for (int k = 0; k < C_DIM; ++k) s += urow[k] * W[k * C_DIM + j];
  Unew[i * C_DIM + j] = s;
  VtNew[j * C_DIM + i] = s;
  if (i == 0) {
    if (st == 0) {
      dnew[j] = bg[j];
      if (bg[j] != 0.0f) *bflag = 1;  // benchmark bias is 0 -> c-path skipped
    } else {
      float t = 0.0f;
      for (int k = 0; k < C_DIM; ++k) t += dprev[k] * W[k * C_DIM + j];
      dnew[j] = t;
    }
  }
}

// ---------------- fused walk step: converged whole-row gathers ----------------
// One wave per node; per edge, all 64 lanes load one dword of the SAME row
// (lane owns channels 2l, 2l+1). Wave-uniform trip count -> no divergence.
__global__ __launch_bounds__(256) void step_kernel(
    const __hip_bfloat16* __restrict__ Gin,
    __hip_bfloat16* __restrict__ Gout,
    const uint2* __restrict__ ell,
    const int* __restrict__ degE,
    const float* __restrict__ cin,
    float* __restrict__ cout,
    const float* __restrict__ Vt,    // (W^{st+1})^T, row-major [128][128]
    const float* __restrict__ dvec,  // d_st = b^T W^st
    float* __restrict__ trG,
    float* __restrict__ ctr,
    const int* __restrict__ bflag,
    int st, int notlast) {
  const int lane = threadIdx.x & 63;
  const int wv   = threadIdx.x >> 6;
  const int node = blockIdx.x * 4 + wv;          // N_TOT = 4*8224 exact

  const uint2* eb = ell + (size_t)node * ELLW;
  const uint2 m  = eb[lane];                     // slot `lane` (coalesced 512B)
  const int cntE = degE[node];                   // wave-uniform (1..64)
  const unsigned* __restrict__ G32 = (const unsigned*)Gin;

  float a0 = 0.0f, a1 = 0.0f;

#pragma unroll 4
  for (int e = 0; e < cntE; ++e) {
    const unsigned nb = (unsigned)__shfl((int)m.x, e);
    const unsigned sb = (unsigned)__shfl((int)m.y, e);
    const unsigned g  = G32[(size_t)sb * 64 + lane];   // converged 256B row read
    const float nv = __uint_as_float(nb);
    a0 += nv * bflo(g);
    a1 += nv * bfhi(g);
  }

  if (notlast) {
    union { __hip_bfloat16 h[2]; unsigned u; } pk;
    pk.h[0] = __float2bfloat16(a0);
    pk.h[1] = __float2bfloat16(a1);
    ((unsigned*)Gout)[(size_t)node * 64 + lane] = pk.u;
  }

  // trace: row `node` contributes dot(G_new[node], Vt[node&127][:])
  const int col = node & 127;
  const float2 v = *(const float2*)(Vt + col * C_DIM + lane * 2);
  float pd = a0 * v.x + a1 * v.y;
  pd += __shfl_xor(pd, 1);
  pd += __shfl_xor(pd, 2);
  pd += __shfl_xor(pd, 4);
  pd += __shfl_xor(pd, 8);
  pd += __shfl_xor(pd, 16);
  pd += __shfl_xor(pd, 32);

  const int bnz = *bflag;
  if (lane == 0) {
    atomicAdd(&trG[st * NTR + (node >> 7)], pd);
    if (bnz) {  // exact bias path (unused when b_gcn == 0)
      float cself = cin[node];
      float cnew = 0.0f;
      for (int p2 = 0; p2 < cntE; ++p2) {
        uint2 e2 = eb[p2];
        cnew += __uint_as_float(e2.x) * cin[e2.y];  // slot0 gives dd*cself
      }
      if (notlast) cout[node] = cnew;
      atomicAdd(&ctr[st * NTR + (node >> 7)], cself * dvec[col]);
    }
  }
}

// ---------------- epilogue ----------------
// trace_t = trG[t] + prefix_sum_{k<=t} ctr[k]  (bias terms accumulate over k)
__global__ __launch_bounds__(256) void final_kernel(const float* __restrict__ trG,
                                                    const float* __restrict__ ctr,
                                                    const float* __restrict__ y,
                                                    const float* __restrict__ W1,
                                                    const float* __restrict__ b1,
                                                    const float* __restrict__ W2,
                                                    const float* __restrict__ b2,
                                                    float* __restrict__ out) {
  __shared__ float sm[B_SZ];
  const int b = threadIdx.x;
  const float sgn = (y[b] - 0.5f) * 2.0f;
  float runb = 0.0f, runn = 0.0f;
  float vals[WALK];
#pragma unroll
  for (int t = 0; t < WALK; ++t) {
    runb += ctr[t * NTR + b];
    runn += ctr[t * NTR + 256];
    vals[t] = ((trG[t * NTR + b] + runb) - (trG[t * NTR + 256] + runn)) * sgn;
  }

  for (int t = 0; t < WALK; ++t) {
    sm[b] = vals[t];
    __syncthreads();
    for (int off = 128; off >= 1; off >>= 1) {
      if (b < off) sm[b] += sm[b + off];
      __syncthreads();
    }
    float mean = sm[0] * (1.0f / 256.0f);
    __syncthreads();
    float d = vals[t] - mean;
    sm[b] = d * d;
    __syncthreads();
    for (int off = 128; off >= 1; off >>= 1) {
      if (b < off) sm[b] += sm[b + off];
      __syncthreads();
    }
    float stdv = sqrtf(sm[0] * (1.0f / 255.0f));  // ddof=1
    __syncthreads();
    vals[t] = d / stdv;
  }

  float o = b2[0];
#pragma unroll
  for (int j = 0; j < 15; ++j) {
    float a = b1[j];
#pragma unroll
    for (int t = 0; t < WALK; ++t) a += vals[t] * W1[t * 15 + j];
    o += fmaxf(a, 0.0f) * W2[j];
  }
  out[b] = 1.0f / (1.0f + expf(-o));
}

}  // namespace

extern "C" void kernel_launch(void* const* d_in, const int* in_sizes, int n_in,
                              void* d_out, int out_size, void* d_ws, size_t ws_size,
                              hipStream_t stream) {
  const float* x_p   = (const float*)d_in[0];
  const float* x_np  = (const float*)d_in[1];
  const float* y     = (const float*)d_in[2];
  const int* ei_p    = (const int*)d_in[3];   // int inputs arrive as int32
  const int* ei_np   = (const int*)d_in[4];
  const float* W_gcn = (const float*)d_in[5];
  const float* b_gcn = (const float*)d_in[6];
  const float* W1    = (const float*)d_in[7];
  const float* b1    = (const float*)d_in[8];
  const float* W2    = (const float*)d_in[9];
  const float* b2    = (const float*)d_in[10];
  float* out         = (float*)d_out;

  char* p = (char*)d_ws;
  auto alloc = [&](size_t bytes) -> void* {
    void* r = (void*)p;
    p += (bytes + 255) & ~(size_t)255;
    return r;
  };
  __hip_bfloat16* Ga = (__hip_bfloat16*)alloc((size_t)N_TOT * C_DIM * 2);  // G ping
  __hip_bfloat16* Gb = (__hip_bfloat16*)alloc((size_t)N_TOT * C_DIM * 2);  // G pong
  uint2* ell      = (uint2*)alloc((size_t)N_TOT * ELLW * 8);     // padded edge list
  int*   degE     = (int*)alloc((size_t)N_TOT * 4);              // slots per node
  float* dinv     = (float*)alloc((size_t)N_TOT * 4);
  int*   cnt      = (int*)alloc((size_t)N_TOT * 4);
  int*   fill     = (int*)alloc((size_t)N_TOT * 4);
  float* ca       = (float*)alloc((size_t)N_TOT * 4);            // c ping
  float* cb       = (float*)alloc((size_t)N_TOT * 4);            // c pong
  float* Ua       = (float*)alloc((size_t)C_DIM * C_DIM * 4);    // W^t ping
  float* Ub       = (float*)alloc((size_t)C_DIM * C_DIM * 4);    // W^t pong
  float* Vt       = (float*)alloc((size_t)C_DIM * C_DIM * 4);    // (W^t)^T
  float* da       = (float*)alloc((size_t)C_DIM * 4);            // d ping
  float* db       = (float*)alloc((size_t)C_DIM * 4);            // d pong
  float* trG      = (float*)alloc((size_t)WALK * NTR * 4);
  float* ctr      = (float*)alloc((size_t)WALK * NTR * 4);
  int*   bflag    = (int*)alloc(4);

  // --- precompute (no ELL memset needed: only slots < degE are read) ---
  init_kernel<<<(N_TOT + 255) / 256, 256, 0, stream>>>(cnt, trG, ctr, Ua, ca, bflag);
  count_kernel<<<(E_TOT + 255) / 256, 256, 0, stream>>>(ei_p, ei_np, cnt);
  dinv_kernel<<<(N_TOT + 255) / 256, 256, 0, stream>>>(cnt, dinv, fill, degE, ell);
  fill_kernel<<<(E_TOT + 255) / 256, 256, 0, stream>>>(ei_p, ei_np, fill, dinv, ell);
  {
    const int NT8 = N_TOT * C_DIM / 8;
    concat_kernel<<<(NT8 + 255) / 256, 256, 0, stream>>>(x_p, x_np, Ga);
  }

  // --- 7 walk steps: tiny W-power + fused converged-gather step ---
  __hip_bfloat16 *Gcur = Ga, *Gnext = Gb;
  float *Ucur = Ua, *Unext = Ub;
  float *ccur = ca, *cnext = cb;
  float *dcur = da, *dnext = db;
  for (int st = 0; st < WALK; ++st) {
    wpow_kernel<<<C_DIM, C_DIM, 0, stream>>>(W_gcn, Ucur, Unext, Vt, dcur, dnext,
                                             b_gcn, bflag, st);
    const int notlast = (st < WALK - 1) ? 1 : 0;
    step_kernel<<<N_TOT / 4, 256, 0, stream>>>(Gcur, Gnext, ell, degE,
                                               ccur, cnext, Vt, dnext,
                                               trG, ctr, bflag, st, notlast);
    { __hip_bfloat16* t = Gcur; Gcur = Gnext; Gnext = t; }
    { float* t = Ucur; Ucur = Unext; Unext = t; }
    { float* t = ccur; ccur = cnext; cnext = t; }
    { float* t = dcur; dcur = dnext; dnext = t; }
  }

  // --- standardize + MLP + sigmoid ---
  final_kernel<<<1, B_SZ, 0, stream>>>(trG, ctr, y, W1, b1, W2, b2, out);
}

// Round 8
// 820.234 us; speedup vs baseline: 1.6864x; 1.2696x over previous
//
#include <hip/hip_runtime.h>
#include <hip/hip_bf16.h>
#include <math.h>

namespace {

constexpr int C_DIM  = 128;
constexpr int B_SZ   = 256;
constexpr int NP_OFF = 32768;         // np-graph node-id offset
constexpr int N_TOT  = 32896;         // 32768 + 128 combined rows
constexpr int E_P    = 524288;
constexpr int E_NP   = 2048;
constexpr int E_TOT  = E_P + E_NP;
constexpr int WALK   = 7;
constexpr int NTR    = 257;           // 256 p-block traces + 1 np trace
constexpr int ESZ    = E_TOT + N_TOT; // edges incl per-node self loop
constexpr int EPAD   = 64;            // tail pad so 64-wide reads never OOB

// Algebra: H_t = A^t H0 W^t + sum_{k<t} (A^k 1)(b^T W^k); only traces needed:
//   trace_t[b] = <G_t[b-rows], (W^t)^T>_F + bias terms (skipped when b==0).
// G_t = A^t H0 propagated sparsely.
//
// R8: R2's quarter-per-node gather structure (best measured: 91.6us/step,
// time ~= FETCH/520GB/s) fed from COMPACT CSR metadata (srcs u32 + norms f32,
// self loop = edge 0) instead of 64-slot padded ELL: metadata FETCH drops
// 16.8MB -> 4.5MB per step. Rounds consume 4 static register banks
// (group rg = r>>2 fully unrolled -> no dynamic reg indexing / scratch).
// Tail edges masked by norm=0 with clamped src (spill reads provably hit
// written slots < 64 of subsequent nodes).

__device__ __forceinline__ float bflo(unsigned int w) { return __uint_as_float(w << 16); }
__device__ __forceinline__ float bfhi(unsigned int w) { return __uint_as_float(w & 0xffff0000u); }

// ---------------- precompute ----------------

__global__ void init_kernel(int* __restrict__ cnt, float* __restrict__ trG,
                            float* __restrict__ ctr, float* __restrict__ c0,
                            int* __restrict__ bflag,
                            unsigned* __restrict__ srcs, float* __restrict__ norms) {
  int i = blockIdx.x * blockDim.x + threadIdx.x;
  if (i < N_TOT) { cnt[i] = 0; c0[i] = 1.0f; }
  if (i < WALK * NTR) { trG[i] = 0.0f; ctr[i] = 0.0f; }
  if (i < EPAD) { srcs[ESZ + i] = 0u; norms[ESZ + i] = 0.0f; }  // tail pad
  if (i == 0) *bflag = 0;
}

// NOTE: harness delivers integer inputs as int32
__global__ void count_kernel(const int* __restrict__ ei_p,
                             const int* __restrict__ ei_np,
                             int* __restrict__ cnt) {
  int e = blockIdx.x * blockDim.x + threadIdx.x;
  if (e < E_P) {
    int d = ei_p[E_P + e];
    atomicAdd(&cnt[d], 1);
  } else if (e < E_TOT) {
    int i = e - E_P;
    int d = ei_np[E_NP + i] + NP_OFF;
    atomicAdd(&cnt[d], 1);
  }
}

// single-block hierarchical exclusive scan of (cnt+1) -> ptr (length N_TOT+1)
__global__ void scan_kernel(const int* __restrict__ cnt, int* __restrict__ ptr) {
  const int T = 1024;
  __shared__ int part[T];
  int tid = threadIdx.x;
  const int chunk = (N_TOT + T - 1) / T;
  int begin = tid * chunk;
  int end = begin + chunk;
  if (end > N_TOT) end = N_TOT;
  int s = 0;
  for (int i = begin; i < end; ++i) s += cnt[i] + 1;
  part[tid] = s;
  __syncthreads();
  for (int off = 1; off < T; off <<= 1) {
    int v = (tid >= off) ? part[tid - off] : 0;
    __syncthreads();
    part[tid] += v;
    __syncthreads();
  }
  if (tid == T - 1) ptr[N_TOT] = part[T - 1];
  int run = (tid == 0) ? 0 : part[tid - 1];
  for (int i = begin; i < end; ++i) { ptr[i] = run; run += cnt[i] + 1; }
}

// dinv + self-loop edge at slot ptr[i]
__global__ void dinv_kernel(const int* __restrict__ cnt, const int* __restrict__ ptr,
                            float* __restrict__ dinv, int* __restrict__ fill,
                            unsigned* __restrict__ srcs, float* __restrict__ norms) {
  int i = blockIdx.x * blockDim.x + threadIdx.x;
  if (i < N_TOT) {
    float di = rsqrtf((float)cnt[i] + 1.0f);  // +1 self loop
    dinv[i] = di;
    fill[i] = 0;
    int p = ptr[i];
    srcs[p] = (unsigned)i;
    norms[p] = di * di;
  }
}

__global__ void fill_kernel(const int* __restrict__ ei_p,
                            const int* __restrict__ ei_np,
                            const int* __restrict__ ptr, int* __restrict__ fill,
                            const float* __restrict__ dinv,
                            unsigned* __restrict__ srcs, float* __restrict__ norms) {
  int e = blockIdx.x * blockDim.x + threadIdx.x;
  int s, d;
  if (e < E_P) {
    s = ei_p[e];
    d = ei_p[E_P + e];
  } else if (e < E_TOT) {
    int i = e - E_P;
    s = ei_np[i] + NP_OFF;
    d = ei_np[E_NP + i] + NP_OFF;
  } else {
    return;
  }
  int k = atomicAdd(&fill[d], 1);              // 0-based among real edges
  if (k < 63) {                                // cap: self + 63 real = 64 slots
    int pos = ptr[d] + 1 + k;
    srcs[pos] = (unsigned)s;
    norms[pos] = dinv[s] * dinv[d];
  }
}

// G0 = round_bf16([x_p ; x_np]); thread handles 8 floats -> one 16B bf16 store
__global__ void concat_kernel(const float* __restrict__ x_p,
                              const float* __restrict__ x_np,
                              __hip_bfloat16* __restrict__ hb) {
  int i = blockIdx.x * blockDim.x + threadIdx.x;  // 8-elem chunk index
  const int NP8 = NP_OFF * C_DIM / 8;
  const int NT8 = N_TOT * C_DIM / 8;
  if (i >= NT8) return;
  const float* src = (i < NP8) ? (x_p + (size_t)i * 8)
                               : (x_np + (size_t)(i - NP8) * 8);
  union { __hip_bfloat16 h[8]; uint4 u; } pk;
#pragma unroll
  for (int j = 0; j < 8; ++j) pk.h[j] = __float2bfloat16(src[j]);
  ((uint4*)hb)[i] = pk.u;
}

// ---------------- all W powers in ONE kernel ----------------
// Block i (i<128) propagates row i of U_t = W^t:  u <- u @ W, storing
// Vt_all[st][j][i] = (W^{st+1})[i][j].  Block 128 propagates dvec
// (dvec_all[st] = b^T W^st) and sets bflag.
__global__ __launch_bounds__(128) void wpow_all_kernel(
    const float* __restrict__ W, float* __restrict__ Vt_all,
    float* __restrict__ dvec_all, const float* __restrict__ bg,
    int* __restrict__ bflag) {
  __shared__ float cur[C_DIM];
  const int i = blockIdx.x;
  const int j = threadIdx.x;
  if (i < C_DIM) {
    float u = W[i * C_DIM + j];                 // U_1 row i
    Vt_all[0 * C_DIM * C_DIM + j * C_DIM + i] = u;
    for (int st = 1; st < WALK; ++st) {
      cur[j] = u;
      __syncthreads();
      float nu = 0.0f;
      for (int k = 0; k < C_DIM; ++k) nu += cur[k] * W[k * C_DIM + j];
      __syncthreads();
      u = nu;
      Vt_all[st * C_DIM * C_DIM + j * C_DIM + i] = u;
    }
  } else {
    float d = bg[j];
    if (d != 0.0f) atomicOr(bflag, 1);
    dvec_all[0 * C_DIM + j] = d;
    for (int st = 1; st < WALK; ++st) {
      cur[j] = d;
      __syncthreads();
      float nd = 0.0f;
      for (int k = 0; k < C_DIM; ++k) nd += cur[k] * W[k * C_DIM + j];
      __syncthreads();
      d = nd;
      dvec_all[st * C_DIM + j] = d;
    }
  }
}

// ---------------- fused walk step (R2 structure, compact CSR) ----------------
// quarter-per-node; 16 nodes per 256-thread block. Lane gathers 16B of the row.
__global__ __launch_bounds__(256) void step_kernel(
    const __hip_bfloat16* __restrict__ Gin,
    __hip_bfloat16* __restrict__ Gout,
    const int* __restrict__ ptr,
    const unsigned* __restrict__ srcs,
    const float* __restrict__ norms,
    const float* __restrict__ cin,
    float* __restrict__ cout,
    const float* __restrict__ Vt,    // (W^{st+1})^T, row-major [128][128]
    const float* __restrict__ dvec,  // d_st = b^T W^st
    float* __restrict__ trG,
    float* __restrict__ ctr,
    const int* __restrict__ bflag,
    int st, int notlast) {
  const int lane = threadIdx.x & 63;
  const int wv   = threadIdx.x >> 6;
  const int q    = lane >> 4;   // quarter = node sub-index
  const int c8   = lane & 15;   // 8-channel (16B) group within row
  const int node = (blockIdx.x * 4 + wv) * 4 + q;   // N_TOT = 16*2056 exact
  const int qb   = q << 4;

  const int p0  = ptr[node];
  int deg = ptr[node + 1] - p0;
  if (deg > 64) deg = 64;                       // matches fill cap

  // 4 register banks of edge metadata: bank X holds logical edges 16X..16X+15
  const unsigned* S = srcs + p0;
  const float*    F = norms + p0;
  unsigned sA = S[c8],      sB = S[16 + c8], sC = S[32 + c8], sD = S[48 + c8];
  float    nA = F[c8],      nB = F[16 + c8], nC = F[32 + c8], nD = F[48 + c8];

  const uint4* __restrict__ G16 = (const uint4*)Gin;

  float acc[8];
#pragma unroll
  for (int i = 0; i < 8; ++i) acc[i] = 0.0f;

  // group rg covers logical edges [16rg, 16rg+16), consumed in rounds of 4
#define GROUP(SX, NX, RG)                                                      \
  if ((RG) * 16 < deg) {                                                       \
    for (int rr = 0; rr < 4; ++rr) {                                           \
      const int j0 = (RG) * 16 + rr * 4;                                       \
      if (j0 >= deg) break;                                                    \
      unsigned s0 = __shfl(SX, qb + rr * 4 + 0);                               \
      unsigned s1 = __shfl(SX, qb + rr * 4 + 1);                               \
      unsigned s2 = __shfl(SX, qb + rr * 4 + 2);                               \
      unsigned s3 = __shfl(SX, qb + rr * 4 + 3);                               \
      float f0 = __shfl(NX, qb + rr * 4 + 0);                                  \
      float f1 = __shfl(NX, qb + rr * 4 + 1);                                  \
      float f2 = __shfl(NX, qb + rr * 4 + 2);                                  \
      float f3 = __shfl(NX, qb + rr * 4 + 3);                                  \
      f1 = (j0 + 1 < deg) ? f1 : 0.0f;                                         \
      f2 = (j0 + 2 < deg) ? f2 : 0.0f;                                         \
      f3 = (j0 + 3 < deg) ? f3 : 0.0f;                                         \
      s0 = s0 < N_TOT ? s0 : 0u;                                               \
      s1 = s1 < N_TOT ? s1 : 0u;                                               \
      s2 = s2 < N_TOT ? s2 : 0u;                                               \
      s3 = s3 < N_TOT ? s3 : 0u;                                               \
      uint4 g0 = G16[(size_t)s0 * 16 + c8];                                    \
      uint4 g1 = G16[(size_t)s1 * 16 + c8];                                    \
      uint4 g2 = G16[(size_t)s2 * 16 + c8];                                    \
      uint4 g3 = G16[(size_t)s3 * 16 + c8];                                    \
      acc[0] += f0 * bflo(g0.x) + f1 * bflo(g1.x) + f2 * bflo(g2.x) + f3 * bflo(g3.x); \
      acc[1] += f0 * bfhi(g0.x) + f1 * bfhi(g1.x) + f2 * bfhi(g2.x) + f3 * bfhi(g3.x); \
      acc[2] += f0 * bflo(g0.y) + f1 * bflo(g1.y) + f2 * bflo(g2.y) + f3 * bflo(g3.y); \
      acc[3] += f0 * bfhi(g0.y) + f1 * bfhi(g1.y) + f2 * bfhi(g2.y) + f3 * bfhi(g3.y); \
      acc[4] += f0 * bflo(g0.z) + f1 * bflo(g1.z) + f2 * bflo(g2.z) + f3 * bflo(g3.z); \
      acc[5] += f0 * bfhi(g0.z) + f1 * bfhi(g1.z) + f2 * bfhi(g2.z) + f3 * bfhi(g3.z); \
      acc[6] += f0 * bflo(g0.w) + f1 * bflo(g1.w) + f2 * bflo(g2.w) + f3 * bflo(g3.w); \
      acc[7] += f0 * bfhi(g0.w) + f1 * bfhi(g1.w) + f2 * bfhi(g2.w) + f3 * bfhi(g3.w); \
    }                                                                          \
  }

  GROUP(sA, nA, 0)
  GROUP(sB, nB, 1)
  GROUP(sC, nC, 2)
  GROUP(sD, nD, 3)
#undef GROUP

  if (notlast) {
    union { __hip_bfloat16 h[8]; uint4 u; } pk;
#pragma unroll
    for (int i = 0; i < 8; ++i) pk.h[i] = __float2bfloat16(acc[i]);
    ((uint4*)Gout)[(size_t)node * 16 + c8] = pk.u;
  }

  // trace: row `node` contributes dot(G_new[node], Vt[node&127][:])
  const int col = node & 127;
  const float4* vr = (const float4*)(Vt + col * C_DIM + c8 * 8);
  const float4 v0 = vr[0];
  const float4 v1 = vr[1];
  float pd = acc[0] * v0.x + acc[1] * v0.y + acc[2] * v0.z + acc[3] * v0.w +
             acc[4] * v1.x + acc[5] * v1.y + acc[6] * v1.z + acc[7] * v1.w;
  pd += __shfl_xor(pd, 1);
  pd += __shfl_xor(pd, 2);
  pd += __shfl_xor(pd, 4);
  pd += __shfl_xor(pd, 8);

  const int bnz = *bflag;
  if (c8 == 0) {
    atomicAdd(&trG[st * NTR + (node >> 7)], pd);
    if (bnz) {  // exact bias path (unused when b_gcn == 0)
      float cself = cin[node];
      float cnew = 0.0f;
      for (int p2 = 0; p2 < deg; ++p2)
        cnew += norms[p0 + p2] * cin[srcs[p0 + p2]];  // edge 0 = dd*cself
      if (notlast) cout[node] = cnew;
      atomicAdd(&ctr[st * NTR + (node >> 7)], cself * dvec[col]);
    }
  }
}

// ---------------- epilogue ----------------
// trace_t = trG[t] + prefix_sum_{k<=t} ctr[k]  (bias terms accumulate over k)
__global__ __launch_bounds__(256) void final_kernel(const float* __restrict__ trG,
                                                    const float* __restrict__ ctr,
                                                    const float* __restrict__ y,
                                                    const float* __restrict__ W1,
                                                    const float* __restrict__ b1,
                                                    const float* __restrict__ W2,
                                                    const float* __restrict__ b2,
                                                    float* __restrict__ out) {
  __shared__ float sm[B_SZ];
  const int b = threadIdx.x;
  const float sgn = (y[b] - 0.5f) * 2.0f;
  float runb = 0.0f, runn = 0.0f;
  float vals[WALK];
#pragma unroll
  for (int t = 0; t < WALK; ++t) {
    runb += ctr[t * NTR + b];
    runn += ctr[t * NTR + 256];
    vals[t] = ((trG[t * NTR + b] + runb) - (trG[t * NTR + 256] + runn)) * sgn;
  }

  for (int t = 0; t < WALK; ++t) {
    sm[b] = vals[t];
    __syncthreads();
    for (int off = 128; off >= 1; off >>= 1) {
      if (b < off) sm[b] += sm[b + off];
      __syncthreads();
    }
    float mean = sm[0] * (1.0f / 256.0f);
    __syncthreads();
    float d = vals[t] - mean;
    sm[b] = d * d;
    __syncthreads();
    for (int off = 128; off >= 1; off >>= 1) {
      if (b < off) sm[b] += sm[b + off];
      __syncthreads();
    }
    float stdv = sqrtf(sm[0] * (1.0f / 255.0f));  // ddof=1
    __syncthreads();
    vals[t] = d / stdv;
  }

  float o = b2[0];
#pragma unroll
  for (int j = 0; j < 15; ++j) {
    float a = b1[j];
#pragma unroll
    for (int t = 0; t < WALK; ++t) a += vals[t] * W1[t * 15 + j];
    o += fmaxf(a, 0.0f) * W2[j];
  }
  out[b] = 1.0f / (1.0f + expf(-o));
}

}  // namespace

extern "C" void kernel_launch(void* const* d_in, const int* in_sizes, int n_in,
                              void* d_out, int out_size, void* d_ws, size_t ws_size,
                              hipStream_t stream) {
  const float* x_p   = (const float*)d_in[0];
  const float* x_np  = (const float*)d_in[1];
  const float* y     = (const float*)d_in[2];
  const int* ei_p    = (const int*)d_in[3];   // int inputs arrive as int32
  const int* ei_np   = (const int*)d_in[4];
  const float* W_gcn = (const float*)d_in[5];
  const float* b_gcn = (const float*)d_in[6];
  const float* W1    = (const float*)d_in[7];
  const float* b1    = (const float*)d_in[8];
  const float* W2    = (const float*)d_in[9];
  const float* b2    = (const float*)d_in[10];
  float* out         = (float*)d_out;

  char* p = (char*)d_ws;
  auto alloc = [&](size_t bytes) -> void* {
    void* r = (void*)p;
    p += (bytes + 255) & ~(size_t)255;
    return r;
  };
  __hip_bfloat16* Ga = (__hip_bfloat16*)alloc((size_t)N_TOT * C_DIM * 2);  // G ping
  __hip_bfloat16* Gb = (__hip_bfloat16*)alloc((size_t)N_TOT * C_DIM * 2);  // G pong
  unsigned* srcs  = (unsigned*)alloc((size_t)(ESZ + EPAD) * 4);  // CSR srcs
  float* norms    = (float*)alloc((size_t)(ESZ + EPAD) * 4);     // CSR norms
  int*   ptr      = (int*)alloc((size_t)(N_TOT + 1) * 4);
  float* dinv     = (float*)alloc((size_t)N_TOT * 4);
  int*   cnt      = (int*)alloc((size_t)N_TOT * 4);
  int*   fill     = (int*)alloc((size_t)N_TOT * 4);
  float* ca       = (float*)alloc((size_t)N_TOT * 4);            // c ping
  float* cb       = (float*)alloc((size_t)N_TOT * 4);            // c pong
  float* Vt_all   = (float*)alloc((size_t)WALK * C_DIM * C_DIM * 4);
  float* dvec_all = (float*)alloc((size_t)WALK * C_DIM * 4);
  float* trG      = (float*)alloc((size_t)WALK * NTR * 4);
  float* ctr      = (float*)alloc((size_t)WALK * NTR * 4);
  int*   bflag    = (int*)alloc(4);

  // --- precompute ---
  init_kernel<<<(N_TOT + 255) / 256, 256, 0, stream>>>(cnt, trG, ctr, ca, bflag,
                                                       srcs, norms);
  count_kernel<<<(E_TOT + 255) / 256, 256, 0, stream>>>(ei_p, ei_np, cnt);
  scan_kernel<<<1, 1024, 0, stream>>>(cnt, ptr);
  dinv_kernel<<<(N_TOT + 255) / 256, 256, 0, stream>>>(cnt, ptr, dinv, fill,
                                                       srcs, norms);
  fill_kernel<<<(E_TOT + 255) / 256, 256, 0, stream>>>(ei_p, ei_np, ptr, fill,
                                                       dinv, srcs, norms);
  {
    const int NT8 = N_TOT * C_DIM / 8;
    concat_kernel<<<(NT8 + 255) / 256, 256, 0, stream>>>(x_p, x_np, Ga);
  }
  wpow_all_kernel<<<C_DIM + 1, C_DIM, 0, stream>>>(W_gcn, Vt_all, dvec_all,
                                                   b_gcn, bflag);

  // --- 7 walk steps ---
  __hip_bfloat16 *Gcur = Ga, *Gnext = Gb;
  float *ccur = ca, *cnext = cb;
  for (int st = 0; st < WALK; ++st) {
    const int notlast = (st < WALK - 1) ? 1 : 0;
    step_kernel<<<N_TOT / 16, 256, 0, stream>>>(Gcur, Gnext, ptr, srcs, norms,
                                                ccur, cnext,
                                                Vt_all + (size_t)st * C_DIM * C_DIM,
                                                dvec_all + (size_t)st * C_DIM,
                                                trG, ctr, bflag, st, notlast);
    { __hip_bfloat16* t = Gcur; Gcur = Gnext; Gnext = t; }
    { float* t = ccur; ccur = cnext; cnext = t; }
  }

  // --- standardize + MLP + sigmoid ---
  final_kernel<<<1, B_SZ, 0, stream>>>(trG, ctr, y, W1, b1, W2, b2, out);
}

// Round 9
// 563.541 us; speedup vs baseline: 2.4546x; 1.4555x over previous
//
#include <hip/hip_runtime.h>
#include <hip/hip_bf16.h>
#include <math.h>

namespace {

constexpr int C_DIM  = 128;
constexpr int B_SZ   = 256;
constexpr int NP_OFF = 32768;         // np-graph node-id offset
constexpr int N_TOT  = 32896;         // 32768 + 128 combined rows
constexpr int E_P    = 524288;
constexpr int E_NP   = 2048;
constexpr int E_TOT  = E_P + E_NP;
constexpr int WALK   = 7;
constexpr int NTR    = 257;           // 256 p-block traces + 1 np trace
constexpr int ESZ    = E_TOT + N_TOT; // edges incl per-node self loop
constexpr int EPAD   = 64;            // tail pad so 64-wide reads never OOB

// Algebra: H_t = A^t H0 W^t + sum_{k<t} (A^k 1)(b^T W^k); only traces needed:
//   trace_t[b] = <G_t[b-rows], (W^t)^T>_F + bias terms (skipped when b==0).
// G_t = A^t H0 propagated sparsely.
//
// R9 experiment: R2/R6/R8 all pinned at ~87-92us/step with time tracking
// {waves x serialized gather rounds}, NOT bytes (R6: half bytes, same time)
// and NOT instructions (R7: 4x inst, 1.5x time). Hypothesis: per-wave chain
// serialization / convoying. Test: each 16-lane quarter owns TWO nodes,
// interleaving their gather rounds (8 uint4 loads in flight vs 4), waves
// halved, instructions/bytes identical. If chain-bound -> ~50-60us steps;
// if chip-global random-service-bound -> null, scatter plateau established.

__device__ __forceinline__ float bflo(unsigned int w) { return __uint_as_float(w << 16); }
__device__ __forceinline__ float bfhi(unsigned int w) { return __uint_as_float(w & 0xffff0000u); }

// ---------------- precompute ----------------

__global__ void init_kernel(int* __restrict__ cnt, float* __restrict__ trG,
                            float* __restrict__ ctr, float* __restrict__ c0,
                            int* __restrict__ bflag,
                            unsigned* __restrict__ srcs, float* __restrict__ norms) {
  int i = blockIdx.x * blockDim.x + threadIdx.x;
  if (i < N_TOT) { cnt[i] = 0; c0[i] = 1.0f; }
  if (i < WALK * NTR) { trG[i] = 0.0f; ctr[i] = 0.0f; }
  if (i < EPAD) { srcs[ESZ + i] = 0u; norms[ESZ + i] = 0.0f; }  // tail pad
  if (i == 0) *bflag = 0;
}

// NOTE: harness delivers integer inputs as int32
__global__ void count_kernel(const int* __restrict__ ei_p,
                             const int* __restrict__ ei_np,
                             int* __restrict__ cnt) {
  int e = blockIdx.x * blockDim.x + threadIdx.x;
  if (e < E_P) {
    int d = ei_p[E_P + e];
    atomicAdd(&cnt[d], 1);
  } else if (e < E_TOT) {
    int i = e - E_P;
    int d = ei_np[E_NP + i] + NP_OFF;
    atomicAdd(&cnt[d], 1);
  }
}

// single-block hierarchical exclusive scan of (cnt+1) -> ptr (length N_TOT+1)
__global__ void scan_kernel(const int* __restrict__ cnt, int* __restrict__ ptr) {
  const int T = 1024;
  __shared__ int part[T];
  int tid = threadIdx.x;
  const int chunk = (N_TOT + T - 1) / T;
  int begin = tid * chunk;
  int end = begin + chunk;
  if (end > N_TOT) end = N_TOT;
  int s = 0;
  for (int i = begin; i < end; ++i) s += cnt[i] + 1;
  part[tid] = s;
  __syncthreads();
  for (int off = 1; off < T; off <<= 1) {
    int v = (tid >= off) ? part[tid - off] : 0;
    __syncthreads();
    part[tid] += v;
    __syncthreads();
  }
  if (tid == T - 1) ptr[N_TOT] = part[T - 1];
  int run = (tid == 0) ? 0 : part[tid - 1];
  for (int i = begin; i < end; ++i) { ptr[i] = run; run += cnt[i] + 1; }
}

// dinv + self-loop edge at slot ptr[i]
__global__ void dinv_kernel(const int* __restrict__ cnt, const int* __restrict__ ptr,
                            float* __restrict__ dinv, int* __restrict__ fill,
                            unsigned* __restrict__ srcs, float* __restrict__ norms) {
  int i = blockIdx.x * blockDim.x + threadIdx.x;
  if (i < N_TOT) {
    float di = rsqrtf((float)cnt[i] + 1.0f);  // +1 self loop
    dinv[i] = di;
    fill[i] = 0;
    int p = ptr[i];
    srcs[p] = (unsigned)i;
    norms[p] = di * di;
  }
}

__global__ void fill_kernel(const int* __restrict__ ei_p,
                            const int* __restrict__ ei_np,
                            const int* __restrict__ ptr, int* __restrict__ fill,
                            const float* __restrict__ dinv,
                            unsigned* __restrict__ srcs, float* __restrict__ norms) {
  int e = blockIdx.x * blockDim.x + threadIdx.x;
  int s, d;
  if (e < E_P) {
    s = ei_p[e];
    d = ei_p[E_P + e];
  } else if (e < E_TOT) {
    int i = e - E_P;
    s = ei_np[i] + NP_OFF;
    d = ei_np[E_NP + i] + NP_OFF;
  } else {
    return;
  }
  int k = atomicAdd(&fill[d], 1);              // 0-based among real edges
  if (k < 63) {                                // cap: self + 63 real = 64 slots
    int pos = ptr[d] + 1 + k;
    srcs[pos] = (unsigned)s;
    norms[pos] = dinv[s] * dinv[d];
  }
}

// G0 = round_bf16([x_p ; x_np]); thread handles 8 floats -> one 16B bf16 store
__global__ void concat_kernel(const float* __restrict__ x_p,
                              const float* __restrict__ x_np,
                              __hip_bfloat16* __restrict__ hb) {
  int i = blockIdx.x * blockDim.x + threadIdx.x;  // 8-elem chunk index
  const int NP8 = NP_OFF * C_DIM / 8;
  const int NT8 = N_TOT * C_DIM / 8;
  if (i >= NT8) return;
  const float* src = (i < NP8) ? (x_p + (size_t)i * 8)
                               : (x_np + (size_t)(i - NP8) * 8);
  union { __hip_bfloat16 h[8]; uint4 u; } pk;
#pragma unroll
  for (int j = 0; j < 8; ++j) pk.h[j] = __float2bfloat16(src[j]);
  ((uint4*)hb)[i] = pk.u;
}

// ---------------- all W powers in ONE kernel ----------------
__global__ __launch_bounds__(128) void wpow_all_kernel(
    const float* __restrict__ W, float* __restrict__ Vt_all,
    float* __restrict__ dvec_all, const float* __restrict__ bg,
    int* __restrict__ bflag) {
  __shared__ float cur[C_DIM];
  const int i = blockIdx.x;
  const int j = threadIdx.x;
  if (i < C_DIM) {
    float u = W[i * C_DIM + j];                 // U_1 row i
    Vt_all[0 * C_DIM * C_DIM + j * C_DIM + i] = u;
    for (int st = 1; st < WALK; ++st) {
      cur[j] = u;
      __syncthreads();
      float nu = 0.0f;
      for (int k = 0; k < C_DIM; ++k) nu += cur[k] * W[k * C_DIM + j];
      __syncthreads();
      u = nu;
      Vt_all[st * C_DIM * C_DIM + j * C_DIM + i] = u;
    }
  } else {
    float d = bg[j];
    if (d != 0.0f) atomicOr(bflag, 1);
    dvec_all[0 * C_DIM + j] = d;
    for (int st = 1; st < WALK; ++st) {
      cur[j] = d;
      __syncthreads();
      float nd = 0.0f;
      for (int k = 0; k < C_DIM; ++k) nd += cur[k] * W[k * C_DIM + j];
      __syncthreads();
      d = nd;
      dvec_all[st * C_DIM + j] = d;
    }
  }
}

// ---------------- fused walk step: 2 nodes per quarter, interleaved ----------
__global__ __launch_bounds__(256, 4) void step_kernel(
    const __hip_bfloat16* __restrict__ Gin,
    __hip_bfloat16* __restrict__ Gout,
    const int* __restrict__ ptr,
    const unsigned* __restrict__ srcs,
    const float* __restrict__ norms,
    const float* __restrict__ cin,
    float* __restrict__ cout,
    const float* __restrict__ Vt,    // (W^{st+1})^T, row-major [128][128]
    const float* __restrict__ dvec,  // d_st = b^T W^st
    float* __restrict__ trG,
    float* __restrict__ ctr,
    const int* __restrict__ bflag,
    int st, int notlast) {
  const int lane = threadIdx.x & 63;
  const int wv   = threadIdx.x >> 6;
  const int q    = lane >> 4;   // quarter
  const int c8   = lane & 15;   // 8-channel (16B) group within row
  const int base = (blockIdx.x * 4 + wv) * 8;       // 8 nodes per wave
  const int n0   = base + 2 * q;                    // N_TOT = 32*1028 exact
  const int n1   = n0 + 1;
  const int qb   = q << 4;

  const int p0 = ptr[n0];
  const int p1 = ptr[n1];
  int d0 = ptr[n0 + 1] - p0; if (d0 > 64) d0 = 64;
  int d1 = ptr[n1 + 1] - p1; if (d1 > 64) d1 = 64;
  const int dmax = d0 > d1 ? d0 : d1;

  // 4 register banks of edge metadata per node (bank X = logical 16X..16X+15)
  const unsigned* S0 = srcs + p0;   const float* F0 = norms + p0;
  const unsigned* S1 = srcs + p1;   const float* F1 = norms + p1;
  unsigned sA0 = S0[c8], sB0 = S0[16 + c8], sC0 = S0[32 + c8], sD0 = S0[48 + c8];
  float    nA0 = F0[c8], nB0 = F0[16 + c8], nC0 = F0[32 + c8], nD0 = F0[48 + c8];
  unsigned sA1 = S1[c8], sB1 = S1[16 + c8], sC1 = S1[32 + c8], sD1 = S1[48 + c8];
  float    nA1 = F1[c8], nB1 = F1[16 + c8], nC1 = F1[32 + c8], nD1 = F1[48 + c8];

  const uint4* __restrict__ G16 = (const uint4*)Gin;

  float acc0[8], acc1[8];
#pragma unroll
  for (int i = 0; i < 8; ++i) { acc0[i] = 0.0f; acc1[i] = 0.0f; }

#define CONS(ACC, F0_, F1_, F2_, F3_, Gg0, Gg1, Gg2, Gg3)                      \
  do {                                                                         \
    ACC[0] += F0_ * bflo(Gg0.x) + F1_ * bflo(Gg1.x) + F2_ * bflo(Gg2.x) + F3_ * bflo(Gg3.x); \
    ACC[1] += F0_ * bfhi(Gg0.x) + F1_ * bfhi(Gg1.x) + F2_ * bfhi(Gg2.x) + F3_ * bfhi(Gg3.x); \
    ACC[2] += F0_ * bflo(Gg0.y) + F1_ * bflo(Gg1.y) + F2_ * bflo(Gg2.y) + F3_ * bflo(Gg3.y); \
    ACC[3] += F0_ * bfhi(Gg0.y) + F1_ * bfhi(Gg1.y) + F2_ * bfhi(Gg2.y) + F3_ * bfhi(Gg3.y); \
    ACC[4] += F0_ * bflo(Gg0.z) + F1_ * bflo(Gg1.z) + F2_ * bflo(Gg2.z) + F3_ * bflo(Gg3.z); \
    ACC[5] += F0_ * bfhi(Gg0.z) + F1_ * bfhi(Gg1.z) + F2_ * bfhi(Gg2.z) + F3_ * bfhi(Gg3.z); \
    ACC[6] += F0_ * bflo(Gg0.w) + F1_ * bflo(Gg1.w) + F2_ * bflo(Gg2.w) + F3_ * bflo(Gg3.w); \
    ACC[7] += F0_ * bfhi(Gg0.w) + F1_ * bfhi(Gg1.w) + F2_ * bfhi(Gg2.w) + F3_ * bfhi(Gg3.w); \
  } while (0)

  // group RG covers logical edges [16RG,16RG+16) for both nodes, rounds of 4;
  // node0's 4 gathers and node1's 4 gathers are both in flight per round.
#define GROUP2(SX0, NX0, SX1, NX1, RG)                                         \
  if ((RG) * 16 < dmax) {                                                      \
    for (int rr = 0; rr < 4; ++rr) {                                           \
      const int j0 = (RG) * 16 + rr * 4;                                       \
      if (j0 >= dmax) break;                                                   \
      unsigned a0 = __shfl(SX0, qb + rr * 4 + 0);                              \
      unsigned a1 = __shfl(SX0, qb + rr * 4 + 1);                              \
      unsigned a2 = __shfl(SX0, qb + rr * 4 + 2);                              \
      unsigned a3 = __shfl(SX0, qb + rr * 4 + 3);                              \
      float e0 = __shfl(NX0, qb + rr * 4 + 0);                                 \
      float e1 = __shfl(NX0, qb + rr * 4 + 1);                                 \
      float e2 = __shfl(NX0, qb + rr * 4 + 2);                                 \
      float e3 = __shfl(NX0, qb + rr * 4 + 3);                                 \
      e0 = (j0 + 0 < d0) ? e0 : 0.0f;                                          \
      e1 = (j0 + 1 < d0) ? e1 : 0.0f;                                          \
      e2 = (j0 + 2 < d0) ? e2 : 0.0f;                                          \
      e3 = (j0 + 3 < d0) ? e3 : 0.0f;                                          \
      a0 = a0 < N_TOT ? a0 : 0u;  a1 = a1 < N_TOT ? a1 : 0u;                   \
      a2 = a2 < N_TOT ? a2 : 0u;  a3 = a3 < N_TOT ? a3 : 0u;                   \
      uint4 g00 = G16[(size_t)a0 * 16 + c8];                                   \
      uint4 g01 = G16[(size_t)a1 * 16 + c8];                                   \
      uint4 g02 = G16[(size_t)a2 * 16 + c8];                                   \
      uint4 g03 = G16[(size_t)a3 * 16 + c8];                                   \
      unsigned b0 = __shfl(SX1, qb + rr * 4 + 0);                              \
      unsigned b1 = __shfl(SX1, qb + rr * 4 + 1);                              \
      unsigned b2 = __shfl(SX1, qb + rr * 4 + 2);                              \
      unsigned b3 = __shfl(SX1, qb + rr * 4 + 3);                              \
      float h0 = __shfl(NX1, qb + rr * 4 + 0);                                 \
      float h1 = __shfl(NX1, qb + rr * 4 + 1);                                 \
      float h2 = __shfl(NX1, qb + rr * 4 + 2);                                 \
      float h3 = __shfl(NX1, qb + rr * 4 + 3);                                 \
      h0 = (j0 + 0 < d1) ? h0 : 0.0f;                                          \
      h1 = (j0 + 1 < d1) ? h1 : 0.0f;                                          \
      h2 = (j0 + 2 < d1) ? h2 : 0.0f;                                          \
      h3 = (j0 + 3 < d1) ? h3 : 0.0f;                                          \
      b0 = b0 < N_TOT ? b0 : 0u;  b1 = b1 < N_TOT ? b1 : 0u;                   \
      b2 = b2 < N_TOT ? b2 : 0u;  b3 = b3 < N_TOT ? b3 : 0u;                   \
      uint4 g10 = G16[(size_t)b0 * 16 + c8];                                   \
      uint4 g11 = G16[(size_t)b1 * 16 + c8];                                   \
      uint4 g12 = G16[(size_t)b2 * 16 + c8];                                   \
      uint4 g13 = G16[(size_t)b3 * 16 + c8];                                   \
      CONS(acc0, e0, e1, e2, e3, g00, g01, g02, g03);                          \
      CONS(acc1, h0, h1, h2, h3, g10, g11, g12, g13);                          \
    }                                                                          \
  }

  GROUP2(sA0, nA0, sA1, nA1, 0)
  GROUP2(sB0, nB0, sB1, nB1, 1)
  GROUP2(sC0, nC0, sC1, nC1, 2)
  GROUP2(sD0, nD0, sD1, nD1, 3)
#undef GROUP2
#undef CONS

  if (notlast) {
    union { __hip_bfloat16 h[8]; uint4 u; } pk0, pk1;
#pragma unroll
    for (int i = 0; i < 8; ++i) { pk0.h[i] = __float2bfloat16(acc0[i]);
                                  pk1.h[i] = __float2bfloat16(acc1[i]); }
    ((uint4*)Gout)[(size_t)n0 * 16 + c8] = pk0.u;
    ((uint4*)Gout)[(size_t)n1 * 16 + c8] = pk1.u;
  }

  // traces: dot(G_new[n], Vt[n&127][:]) per node
  const int col0 = n0 & 127;
  const int col1 = n1 & 127;
  const float4* vr0 = (const float4*)(Vt + col0 * C_DIM + c8 * 8);
  const float4* vr1 = (const float4*)(Vt + col1 * C_DIM + c8 * 8);
  const float4 v00 = vr0[0], v01 = vr0[1];
  const float4 v10 = vr1[0], v11 = vr1[1];
  float pd0 = acc0[0] * v00.x + acc0[1] * v00.y + acc0[2] * v00.z + acc0[3] * v00.w +
              acc0[4] * v01.x + acc0[5] * v01.y + acc0[6] * v01.z + acc0[7] * v01.w;
  float pd1 = acc1[0] * v10.x + acc1[1] * v10.y + acc1[2] * v10.z + acc1[3] * v10.w +
              acc1[4] * v11.x + acc1[5] * v11.y + acc1[6] * v11.z + acc1[7] * v11.w;
  pd0 += __shfl_xor(pd0, 1);  pd1 += __shfl_xor(pd1, 1);
  pd0 += __shfl_xor(pd0, 2);  pd1 += __shfl_xor(pd1, 2);
  pd0 += __shfl_xor(pd0, 4);  pd1 += __shfl_xor(pd1, 4);
  pd0 += __shfl_xor(pd0, 8);  pd1 += __shfl_xor(pd1, 8);

  const int bnz = *bflag;
  if (c8 == 0) {
    atomicAdd(&trG[st * NTR + (n0 >> 7)], pd0 + pd1);  // n0,n1 same block row
    if (bnz) {  // exact bias path (unused when b_gcn == 0)
      float cs0 = cin[n0], cn0 = 0.0f;
      for (int p2 = 0; p2 < d0; ++p2)
        cn0 += norms[p0 + p2] * cin[srcs[p0 + p2]];
      float cs1 = cin[n1], cn1 = 0.0f;
      for (int p2 = 0; p2 < d1; ++p2)
        cn1 += norms[p1 + p2] * cin[srcs[p1 + p2]];
      if (notlast) { cout[n0] = cn0; cout[n1] = cn1; }
      atomicAdd(&ctr[st * NTR + (n0 >> 7)], cs0 * dvec[col0] + cs1 * dvec[col1]);
    }
  }
}

// ---------------- epilogue ----------------
__global__ __launch_bounds__(256) void final_kernel(const float* __restrict__ trG,
                                                    const float* __restrict__ ctr,
                                                    const float* __restrict__ y,
                                                    const float* __restrict__ W1,
                                                    const float* __restrict__ b1,
                                                    const float* __restrict__ W2,
                                                    const float* __restrict__ b2,
                                                    float* __restrict__ out) {
  __shared__ float sm[B_SZ];
  const int b = threadIdx.x;
  const float sgn = (y[b] - 0.5f) * 2.0f;
  float runb = 0.0f, runn = 0.0f;
  float vals[WALK];
#pragma unroll
  for (int t = 0; t < WALK; ++t) {
    runb += ctr[t * NTR + b];
    runn += ctr[t * NTR + 256];
    vals[t] = ((trG[t * NTR + b] + runb) - (trG[t * NTR + 256] + runn)) * sgn;
  }

  for (int t = 0; t < WALK; ++t) {
    sm[b] = vals[t];
    __syncthreads();
    for (int off = 128; off >= 1; off >>= 1) {
      if (b < off) sm[b] += sm[b + off];
      __syncthreads();
    }
    float mean = sm[0] * (1.0f / 256.0f);
    __syncthreads();
    float d = vals[t] - mean;
    sm[b] = d * d;
    __syncthreads();
    for (int off = 128; off >= 1; off >>= 1) {
      if (b < off) sm[b] += sm[b + off];
      __syncthreads();
    }
    float stdv = sqrtf(sm[0] * (1.0f / 255.0f));  // ddof=1
    __syncthreads();
    vals[t] = d / stdv;
  }

  float o = b2[0];
#pragma unroll
  for (int j = 0; j < 15; ++j) {
    float a = b1[j];
#pragma unroll
    for (int t = 0; t < WALK; ++t) a += vals[t] * W1[t * 15 + j];
    o += fmaxf(a, 0.0f) * W2[j];
  }
  out[b] = 1.0f / (1.0f + expf(-o));
}

}  // namespace

extern "C" void kernel_launch(void* const* d_in, const int* in_sizes, int n_in,
                              void* d_out, int out_size, void* d_ws, size_t ws_size,
                              hipStream_t stream) {
  const float* x_p   = (const float*)d_in[0];
  const float* x_np  = (const float*)d_in[1];
  const float* y     = (const float*)d_in[2];
  const int* ei_p    = (const int*)d_in[3];   // int inputs arrive as int32
  const int* ei_np   = (const int*)d_in[4];
  const float* W_gcn = (const float*)d_in[5];
  const float* b_gcn = (const float*)d_in[6];
  const float* W1    = (const float*)d_in[7];
  const float* b1    = (const float*)d_in[8];
  const float* W2    = (const float*)d_in[9];
  const float* b2    = (const float*)d_in[10];
  float* out         = (float*)d_out;

  char* p = (char*)d_ws;
  auto alloc = [&](size_t bytes) -> void* {
    void* r = (void*)p;
    p += (bytes + 255) & ~(size_t)255;
    return r;
  };
  __hip_bfloat16* Ga = (__hip_bfloat16*)alloc((size_t)N_TOT * C_DIM * 2);  // G ping
  __hip_bfloat16* Gb = (__hip_bfloat16*)alloc((size_t)N_TOT * C_DIM * 2);  // G pong
  unsigned* srcs  = (unsigned*)alloc((size_t)(ESZ + EPAD) * 4);  // CSR srcs
  float* norms    = (float*)alloc((size_t)(ESZ + EPAD) * 4);     // CSR norms
  int*   ptr      = (int*)alloc((size_t)(N_TOT + 1) * 4);
  float* dinv     = (float*)alloc((size_t)N_TOT * 4);
  int*   cnt      = (int*)alloc((size_t)N_TOT * 4);
  int*   fill     = (int*)alloc((size_t)N_TOT * 4);
  float* ca       = (float*)alloc((size_t)N_TOT * 4);            // c ping
  float* cb       = (float*)alloc((size_t)N_TOT * 4);            // c pong
  float* Vt_all   = (float*)alloc((size_t)WALK * C_DIM * C_DIM * 4);
  float* dvec_all = (float*)alloc((size_t)WALK * C_DIM * 4);
  float* trG      = (float*)alloc((size_t)WALK * NTR * 4);
  float* ctr      = (float*)alloc((size_t)WALK * NTR * 4);
  int*   bflag    = (int*)alloc(4);

  // --- precompute ---
  init_kernel<<<(N_TOT + 255) / 256, 256, 0, stream>>>(cnt, trG, ctr, ca, bflag,
                                                       srcs, norms);
  count_kernel<<<(E_TOT + 255) / 256, 256, 0, stream>>>(ei_p, ei_np, cnt);
  scan_kernel<<<1, 1024, 0, stream>>>(cnt, ptr);
  dinv_kernel<<<(N_TOT + 255) / 256, 256, 0, stream>>>(cnt, ptr, dinv, fill,
                                                       srcs, norms);
  fill_kernel<<<(E_TOT + 255) / 256, 256, 0, stream>>>(ei_p, ei_np, ptr, fill,
                                                       dinv, srcs, norms);
  {
    const int NT8 = N_TOT * C_DIM / 8;
    concat_kernel<<<(NT8 + 255) / 256, 256, 0, stream>>>(x_p, x_np, Ga);
  }
  wpow_all_kernel<<<C_DIM + 1, C_DIM, 0, stream>>>(W_gcn, Vt_all, dvec_all,
                                                   b_gcn, bflag);

  // --- 7 walk steps ---
  __hip_bfloat16 *Gcur = Ga, *Gnext = Gb;
  float *ccur = ca, *cnext = cb;
  for (int st = 0; st < WALK; ++st) {
    const int notlast = (st < WALK - 1) ? 1 : 0;
    step_kernel<<<N_TOT / 32, 256, 0, stream>>>(Gcur, Gnext, ptr, srcs, norms,
                                                ccur, cnext,
                                                Vt_all + (size_t)st * C_DIM * C_DIM,
                                                dvec_all + (size_t)st * C_DIM,
                                                trG, ctr, bflag, st, notlast);
    { __hip_bfloat16* t = Gcur; Gcur = Gnext; Gnext = t; }
    { float* t = ccur; ccur = cnext; cnext = t; }
  }

  // --- standardize + MLP + sigmoid ---
  final_kernel<<<1, B_SZ, 0, stream>>>(trG, ctr, y, W1, b1, W2, b2, out);
}

// Round 11
// 476.268 us; speedup vs baseline: 2.9043x; 1.1832x over previous
//
#include <hip/hip_runtime.h>
#include <hip/hip_bf16.h>
#include <math.h>

namespace {

constexpr int C_DIM  = 128;
constexpr int B_SZ   = 256;
constexpr int NP_OFF = 32768;         // np-graph node-id offset
constexpr int N_TOT  = 32896;         // 32768 + 128 combined rows
constexpr int E_P    = 524288;
constexpr int E_NP   = 2048;
constexpr int E_TOT  = E_P + E_NP;
constexpr int WALK   = 7;
constexpr int NTR    = 257;           // 256 p-block traces + 1 np trace
constexpr int ESZ    = E_TOT + N_TOT; // edges incl per-node self loop
constexpr int EPAD   = 64;            // tail pad so 64-wide reads never OOB

// Algebra: H_t = A^t H0 W^t + sum_{k<t} (A^k 1)(b^T W^k); only traces needed:
//   trace_t[b] = <G_t[b-rows], (W^t)^T>_F + bias terms (skipped when b==0).
// G_t = A^t H0 propagated sparsely.
//
// R11 (= R10 with the macro-pasting bug fixed: letter suffixes so `a.x`
// doesn't lex as a pp-number): the gather is per-wave CHAIN-LATENCY bound
// (R9: 2 nodes/quarter, 8 gathers in flight, 88->51.5us/step). Same lever
// again: 4 nodes per quarter, 16 independent row-gathers in flight per
// round, waves halved again. All register indexing static.

__device__ __forceinline__ float bflo(unsigned int w) { return __uint_as_float(w << 16); }
__device__ __forceinline__ float bfhi(unsigned int w) { return __uint_as_float(w & 0xffff0000u); }

// ---------------- precompute ----------------

__global__ void init_kernel(int* __restrict__ cnt, float* __restrict__ trG,
                            float* __restrict__ ctr, float* __restrict__ c0,
                            int* __restrict__ bflag,
                            unsigned* __restrict__ srcs, float* __restrict__ norms) {
  int i = blockIdx.x * blockDim.x + threadIdx.x;
  if (i < N_TOT) { cnt[i] = 0; c0[i] = 1.0f; }
  if (i < WALK * NTR) { trG[i] = 0.0f; ctr[i] = 0.0f; }
  if (i < EPAD) { srcs[ESZ + i] = 0u; norms[ESZ + i] = 0.0f; }  // tail pad
  if (i == 0) *bflag = 0;
}

// NOTE: harness delivers integer inputs as int32
__global__ void count_kernel(const int* __restrict__ ei_p,
                             const int* __restrict__ ei_np,
                             int* __restrict__ cnt) {
  int e = blockIdx.x * blockDim.x + threadIdx.x;
  if (e < E_P) {
    int d = ei_p[E_P + e];
    atomicAdd(&cnt[d], 1);
  } else if (e < E_TOT) {
    int i = e - E_P;
    int d = ei_np[E_NP + i] + NP_OFF;
    atomicAdd(&cnt[d], 1);
  }
}

// single-block hierarchical exclusive scan of (cnt+1) -> ptr (length N_TOT+1)
__global__ void scan_kernel(const int* __restrict__ cnt, int* __restrict__ ptr) {
  const int T = 1024;
  __shared__ int part[T];
  int tid = threadIdx.x;
  const int chunk = (N_TOT + T - 1) / T;
  int begin = tid * chunk;
  int end = begin + chunk;
  if (end > N_TOT) end = N_TOT;
  int s = 0;
  for (int i = begin; i < end; ++i) s += cnt[i] + 1;
  part[tid] = s;
  __syncthreads();
  for (int off = 1; off < T; off <<= 1) {
    int v = (tid >= off) ? part[tid - off] : 0;
    __syncthreads();
    part[tid] += v;
    __syncthreads();
  }
  if (tid == T - 1) ptr[N_TOT] = part[T - 1];
  int run = (tid == 0) ? 0 : part[tid - 1];
  for (int i = begin; i < end; ++i) { ptr[i] = run; run += cnt[i] + 1; }
}

// dinv + self-loop edge at slot ptr[i]
__global__ void dinv_kernel(const int* __restrict__ cnt, const int* __restrict__ ptr,
                            float* __restrict__ dinv, int* __restrict__ fill,
                            unsigned* __restrict__ srcs, float* __restrict__ norms) {
  int i = blockIdx.x * blockDim.x + threadIdx.x;
  if (i < N_TOT) {
    float di = rsqrtf((float)cnt[i] + 1.0f);  // +1 self loop
    dinv[i] = di;
    fill[i] = 0;
    int p = ptr[i];
    srcs[p] = (unsigned)i;
    norms[p] = di * di;
  }
}

__global__ void fill_kernel(const int* __restrict__ ei_p,
                            const int* __restrict__ ei_np,
                            const int* __restrict__ ptr, int* __restrict__ fill,
                            const float* __restrict__ dinv,
                            unsigned* __restrict__ srcs, float* __restrict__ norms) {
  int e = blockIdx.x * blockDim.x + threadIdx.x;
  int s, d;
  if (e < E_P) {
    s = ei_p[e];
    d = ei_p[E_P + e];
  } else if (e < E_TOT) {
    int i = e - E_P;
    s = ei_np[i] + NP_OFF;
    d = ei_np[E_NP + i] + NP_OFF;
  } else {
    return;
  }
  int k = atomicAdd(&fill[d], 1);              // 0-based among real edges
  if (k < 63) {                                // cap: self + 63 real = 64 slots
    int pos = ptr[d] + 1 + k;
    srcs[pos] = (unsigned)s;
    norms[pos] = dinv[s] * dinv[d];
  }
}

// G0 = round_bf16([x_p ; x_np]); thread handles 8 floats -> one 16B bf16 store
__global__ void concat_kernel(const float* __restrict__ x_p,
                              const float* __restrict__ x_np,
                              __hip_bfloat16* __restrict__ hb) {
  int i = blockIdx.x * blockDim.x + threadIdx.x;  // 8-elem chunk index
  const int NP8 = NP_OFF * C_DIM / 8;
  const int NT8 = N_TOT * C_DIM / 8;
  if (i >= NT8) return;
  const float* src = (i < NP8) ? (x_p + (size_t)i * 8)
                               : (x_np + (size_t)(i - NP8) * 8);
  union { __hip_bfloat16 h[8]; uint4 u; } pk;
#pragma unroll
  for (int j = 0; j < 8; ++j) pk.h[j] = __float2bfloat16(src[j]);
  ((uint4*)hb)[i] = pk.u;
}

// ---------------- all W powers in ONE kernel ----------------
__global__ __launch_bounds__(128) void wpow_all_kernel(
    const float* __restrict__ W, float* __restrict__ Vt_all,
    float* __restrict__ dvec_all, const float* __restrict__ bg,
    int* __restrict__ bflag) {
  __shared__ float cur[C_DIM];
  const int i = blockIdx.x;
  const int j = threadIdx.x;
  if (i < C_DIM) {
    float u = W[i * C_DIM + j];                 // U_1 row i
    Vt_all[0 * C_DIM * C_DIM + j * C_DIM + i] = u;
    for (int st = 1; st < WALK; ++st) {
      cur[j] = u;
      __syncthreads();
      float nu = 0.0f;
      for (int k = 0; k < C_DIM; ++k) nu += cur[k] * W[k * C_DIM + j];
      __syncthreads();
      u = nu;
      Vt_all[st * C_DIM * C_DIM + j * C_DIM + i] = u;
    }
  } else {
    float d = bg[j];
    if (d != 0.0f) atomicOr(bflag, 1);
    dvec_all[0 * C_DIM + j] = d;
    for (int st = 1; st < WALK; ++st) {
      cur[j] = d;
      __syncthreads();
      float nd = 0.0f;
      for (int k = 0; k < C_DIM; ++k) nd += cur[k] * W[k * C_DIM + j];
      __syncthreads();
      d = nd;
      dvec_all[st * C_DIM + j] = d;
    }
  }
}

// ---------------- fused walk step: 4 nodes per quarter, interleaved ----------
__global__ __launch_bounds__(256) void step_kernel(
    const __hip_bfloat16* __restrict__ Gin,
    __hip_bfloat16* __restrict__ Gout,
    const int* __restrict__ ptr,
    const unsigned* __restrict__ srcs,
    const float* __restrict__ norms,
    const float* __restrict__ cin,
    float* __restrict__ cout,
    const float* __restrict__ Vt,    // (W^{st+1})^T, row-major [128][128]
    const float* __restrict__ dvec,  // d_st = b^T W^st
    float* __restrict__ trG,
    float* __restrict__ ctr,
    const int* __restrict__ bflag,
    int st, int notlast) {
  const int lane = threadIdx.x & 63;
  const int wv   = threadIdx.x >> 6;
  const int q    = lane >> 4;   // quarter
  const int c8   = lane & 15;   // 8-channel (16B) group within row
  const int base = (blockIdx.x * 4 + wv) * 16;      // 16 nodes per wave
  const int n0   = base + 4 * q;                    // N_TOT = 64*514 exact
  const int n1   = n0 + 1;
  const int n2   = n0 + 2;
  const int n3   = n0 + 3;
  const int qb   = q << 4;

  const int p0 = ptr[n0];
  const int p1 = ptr[n1];
  const int p2 = ptr[n2];
  const int p3 = ptr[n3];
  int d0 = ptr[n0 + 1] - p0; if (d0 > 64) d0 = 64;
  int d1 = ptr[n1 + 1] - p1; if (d1 > 64) d1 = 64;
  int d2 = ptr[n2 + 1] - p2; if (d2 > 64) d2 = 64;
  int d3 = ptr[n3 + 1] - p3; if (d3 > 64) d3 = 64;
  int dmax = d0 > d1 ? d0 : d1;
  dmax = dmax > d2 ? dmax : d2;
  dmax = dmax > d3 ? dmax : d3;

  // 4 register banks of edge metadata per node (bank X = logical 16X..16X+15)
  const unsigned* S0 = srcs + p0;   const float* F0 = norms + p0;
  const unsigned* S1 = srcs + p1;   const float* F1 = norms + p1;
  const unsigned* S2 = srcs + p2;   const float* F2 = norms + p2;
  const unsigned* S3 = srcs + p3;   const float* F3 = norms + p3;
  unsigned sA0 = S0[c8], sB0 = S0[16 + c8], sC0 = S0[32 + c8], sD0 = S0[48 + c8];
  float    nA0 = F0[c8], nB0 = F0[16 + c8], nC0 = F0[32 + c8], nD0 = F0[48 + c8];
  unsigned sA1 = S1[c8], sB1 = S1[16 + c8], sC1 = S1[32 + c8], sD1 = S1[48 + c8];
  float    nA1 = F1[c8], nB1 = F1[16 + c8], nC1 = F1[32 + c8], nD1 = F1[48 + c8];
  unsigned sA2 = S2[c8], sB2 = S2[16 + c8], sC2 = S2[32 + c8], sD2 = S2[48 + c8];
  float    nA2 = F2[c8], nB2 = F2[16 + c8], nC2 = F2[32 + c8], nD2 = F2[48 + c8];
  unsigned sA3 = S3[c8], sB3 = S3[16 + c8], sC3 = S3[32 + c8], sD3 = S3[48 + c8];
  float    nA3 = F3[c8], nB3 = F3[16 + c8], nC3 = F3[32 + c8], nD3 = F3[48 + c8];

  const uint4* __restrict__ G16 = (const uint4*)Gin;

  float acc0[8], acc1[8], acc2[8], acc3[8];
#pragma unroll
  for (int i = 0; i < 8; ++i) { acc0[i] = 0.0f; acc1[i] = 0.0f;
                                acc2[i] = 0.0f; acc3[i] = 0.0f; }

  // Issue 4 gathers for node K this round. Letter suffixes (a..d) keep the
  // pasted name away from `.member` (pp-number pitfall: `0.x` is one token).
#define LOADN(K, SX, NX, DK)                                                   \
    unsigned x##K##a = __shfl(SX, qb + rr * 4 + 0);                            \
    unsigned x##K##b = __shfl(SX, qb + rr * 4 + 1);                            \
    unsigned x##K##c = __shfl(SX, qb + rr * 4 + 2);                            \
    unsigned x##K##d = __shfl(SX, qb + rr * 4 + 3);                            \
    float w##K##a = __shfl(NX, qb + rr * 4 + 0);                               \
    float w##K##b = __shfl(NX, qb + rr * 4 + 1);                               \
    float w##K##c = __shfl(NX, qb + rr * 4 + 2);                               \
    float w##K##d = __shfl(NX, qb + rr * 4 + 3);                               \
    w##K##a = (j0 + 0 < DK) ? w##K##a : 0.0f;                                  \
    w##K##b = (j0 + 1 < DK) ? w##K##b : 0.0f;                                  \
    w##K##c = (j0 + 2 < DK) ? w##K##c : 0.0f;                                  \
    w##K##d = (j0 + 3 < DK) ? w##K##d : 0.0f;                                  \
    x##K##a = x##K##a < N_TOT ? x##K##a : 0u;                                  \
    x##K##b = x##K##b < N_TOT ? x##K##b : 0u;                                  \
    x##K##c = x##K##c < N_TOT ? x##K##c : 0u;                                  \
    x##K##d = x##K##d < N_TOT ? x##K##d : 0u;                                  \
    uint4 g##K##a = G16[(size_t)x##K##a * 16 + c8];                            \
    uint4 g##K##b = G16[(size_t)x##K##b * 16 + c8];                            \
    uint4 g##K##c = G16[(size_t)x##K##c * 16 + c8];                            \
    uint4 g##K##d = G16[(size_t)x##K##d * 16 + c8];

#define CONSN(K, ACC)                                                          \
    ACC[0] += w##K##a * bflo(g##K##a.x) + w##K##b * bflo(g##K##b.x)            \
            + w##K##c * bflo(g##K##c.x) + w##K##d * bflo(g##K##d.x);           \
    ACC[1] += w##K##a * bfhi(g##K##a.x) + w##K##b * bfhi(g##K##b.x)            \
            + w##K##c * bfhi(g##K##c.x) + w##K##d * bfhi(g##K##d.x);           \
    ACC[2] += w##K##a * bflo(g##K##a.y) + w##K##b * bflo(g##K##b.y)            \
            + w##K##c * bflo(g##K##c.y) + w##K##d * bflo(g##K##d.y);           \
    ACC[3] += w##K##a * bfhi(g##K##a.y) + w##K##b * bfhi(g##K##b.y)            \
            + w##K##c * bfhi(g##K##c.y) + w##K##d * bfhi(g##K##d.y);           \
    ACC[4] += w##K##a * bflo(g##K##a.z) + w##K##b * bflo(g##K##b.z)            \
            + w##K##c * bflo(g##K##c.z) + w##K##d * bflo(g##K##d.z);           \
    ACC[5] += w##K##a * bfhi(g##K##a.z) + w##K##b * bfhi(g##K##b.z)            \
            + w##K##c * bfhi(g##K##c.z) + w##K##d * bfhi(g##K##d.z);           \
    ACC[6] += w##K##a * bflo(g##K##a.w) + w##K##b * bflo(g##K##b.w)            \
            + w##K##c * bflo(g##K##c.w) + w##K##d * bflo(g##K##d.w);           \
    ACC[7] += w##K##a * bfhi(g##K##a.w) + w##K##b * bfhi(g##K##b.w)            \
            + w##K##c * bfhi(g##K##c.w) + w##K##d * bfhi(g##K##d.w);

#define GROUP4(SX0, NX0, SX1, NX1, SX2, NX2, SX3, NX3, RG)                     \
  if ((RG) * 16 < dmax) {                                                      \
    for (int rr = 0; rr < 4; ++rr) {                                           \
      const int j0 = (RG) * 16 + rr * 4;                                       \
      if (j0 >= dmax) break;                                                   \
      LOADN(0, SX0, NX0, d0)                                                   \
      LOADN(1, SX1, NX1, d1)                                                   \
      LOADN(2, SX2, NX2, d2)                                                   \
      LOADN(3, SX3, NX3, d3)                                                   \
      CONSN(0, acc0)                                                           \
      CONSN(1, acc1)                                                           \
      CONSN(2, acc2)                                                           \
      CONSN(3, acc3)                                                           \
    }                                                                          \
  }

  GROUP4(sA0, nA0, sA1, nA1, sA2, nA2, sA3, nA3, 0)
  GROUP4(sB0, nB0, sB1, nB1, sB2, nB2, sB3, nB3, 1)
  GROUP4(sC0, nC0, sC1, nC1, sC2, nC2, sC3, nC3, 2)
  GROUP4(sD0, nD0, sD1, nD1, sD2, nD2, sD3, nD3, 3)
#undef GROUP4
#undef CONSN
#undef LOADN

  if (notlast) {
    union { __hip_bfloat16 h[8]; uint4 u; } pk0, pk1, pk2, pk3;
#pragma unroll
    for (int i = 0; i < 8; ++i) { pk0.h[i] = __float2bfloat16(acc0[i]);
                                  pk1.h[i] = __float2bfloat16(acc1[i]);
                                  pk2.h[i] = __float2bfloat16(acc2[i]);
                                  pk3.h[i] = __float2bfloat16(acc3[i]); }
    ((uint4*)Gout)[(size_t)n0 * 16 + c8] = pk0.u;
    ((uint4*)Gout)[(size_t)n1 * 16 + c8] = pk1.u;
    ((uint4*)Gout)[(size_t)n2 * 16 + c8] = pk2.u;
    ((uint4*)Gout)[(size_t)n3 * 16 + c8] = pk3.u;
  }

  // traces: dot(G_new[n], Vt[n&127][:]); n0..n3 share the same 128-block
  const int col0 = n0 & 127, col1 = n1 & 127, col2 = n2 & 127, col3 = n3 & 127;
  const float4* vr0 = (const float4*)(Vt + col0 * C_DIM + c8 * 8);
  const float4* vr1 = (const float4*)(Vt + col1 * C_DIM + c8 * 8);
  const float4* vr2 = (const float4*)(Vt + col2 * C_DIM + c8 * 8);
  const float4* vr3 = (const float4*)(Vt + col3 * C_DIM + c8 * 8);
  const float4 v00 = vr0[0], v01 = vr0[1];
  const float4 v10 = vr1[0], v11 = vr1[1];
  const float4 v20 = vr2[0], v21 = vr2[1];
  const float4 v30 = vr3[0], v31 = vr3[1];
  float pd = acc0[0] * v00.x + acc0[1] * v00.y + acc0[2] * v00.z + acc0[3] * v00.w +
             acc0[4] * v01.x + acc0[5] * v01.y + acc0[6] * v01.z + acc0[7] * v01.w;
  pd      += acc1[0] * v10.x + acc1[1] * v10.y + acc1[2] * v10.z + acc1[3] * v10.w +
             acc1[4] * v11.x + acc1[5] * v11.y + acc1[6] * v11.z + acc1[7] * v11.w;
  pd      += acc2[0] * v20.x + acc2[1] * v20.y + acc2[2] * v20.z + acc2[3] * v20.w +
             acc2[4] * v21.x + acc2[5] * v21.y + acc2[6] * v21.z + acc2[7] * v21.w;
  pd      += acc3[0] * v30.x + acc3[1] * v30.y + acc3[2] * v30.z + acc3[3] * v30.w +
             acc3[4] * v31.x + acc3[5] * v31.y + acc3[6] * v31.z + acc3[7] * v31.w;
  pd += __shfl_xor(pd, 1);
  pd += __shfl_xor(pd, 2);
  pd += __shfl_xor(pd, 4);
  pd += __shfl_xor(pd, 8);

  const int bnz = *bflag;
  if (c8 == 0) {
    atomicAdd(&trG[st * NTR + (n0 >> 7)], pd);
    if (bnz) {  // exact bias path (unused when b_gcn == 0)
      float cs0 = cin[n0], cn0 = 0.0f;
      for (int e = 0; e < d0; ++e) cn0 += norms[p0 + e] * cin[srcs[p0 + e]];
      float cs1 = cin[n1], cn1 = 0.0f;
      for (int e = 0; e < d1; ++e) cn1 += norms[p1 + e] * cin[srcs[p1 + e]];
      float cs2 = cin[n2], cn2 = 0.0f;
      for (int e = 0; e < d2; ++e) cn2 += norms[p2 + e] * cin[srcs[p2 + e]];
      float cs3 = cin[n3], cn3 = 0.0f;
      for (int e = 0; e < d3; ++e) cn3 += norms[p3 + e] * cin[srcs[p3 + e]];
      if (notlast) { cout[n0] = cn0; cout[n1] = cn1;
                     cout[n2] = cn2; cout[n3] = cn3; }
      atomicAdd(&ctr[st * NTR + (n0 >> 7)],
                cs0 * dvec[col0] + cs1 * dvec[col1] +
                cs2 * dvec[col2] + cs3 * dvec[col3]);
    }
  }
}

// ---------------- epilogue ----------------
__global__ __launch_bounds__(256) void final_kernel(const float* __restrict__ trG,
                                                    const float* __restrict__ ctr,
                                                    const float* __restrict__ y,
                                                    const float* __restrict__ W1,
                                                    const float* __restrict__ b1,
                                                    const float* __restrict__ W2,
                                                    const float* __restrict__ b2,
                                                    float* __restrict__ out) {
  __shared__ float sm[B_SZ];
  const int b = threadIdx.x;
  const float sgn = (y[b] - 0.5f) * 2.0f;
  float runb = 0.0f, runn = 0.0f;
  float vals[WALK];
#pragma unroll
  for (int t = 0; t < WALK; ++t) {
    runb += ctr[t * NTR + b];
    runn += ctr[t * NTR + 256];
    vals[t] = ((trG[t * NTR + b] + runb) - (trG[t * NTR + 256] + runn)) * sgn;
  }

  for (int t = 0; t < WALK; ++t) {
    sm[b] = vals[t];
    __syncthreads();
    for (int off = 128; off >= 1; off >>= 1) {
      if (b < off) sm[b] += sm[b + off];
      __syncthreads();
    }
    float mean = sm[0] * (1.0f / 256.0f);
    __syncthreads();
    float d = vals[t] - mean;
    sm[b] = d * d;
    __syncthreads();
    for (int off = 128; off >= 1; off >>= 1) {
      if (b < off) sm[b] += sm[b + off];
      __syncthreads();
    }
    float stdv = sqrtf(sm[0] * (1.0f / 255.0f));  // ddof=1
    __syncthreads();
    vals[t] = d / stdv;
  }

  float o = b2[0];
#pragma unroll
  for (int j = 0; j < 15; ++j) {
    float a = b1[j];
#pragma unroll
    for (int t = 0; t < WALK; ++t) a += vals[t] * W1[t * 15 + j];
    o += fmaxf(a, 0.0f) * W2[j];
  }
  out[b] = 1.0f / (1.0f + expf(-o));
}

}  // namespace

extern "C" void kernel_launch(void* const* d_in, const int* in_sizes, int n_in,
                              void* d_out, int out_size, void* d_ws, size_t ws_size,
                              hipStream_t stream) {
  const float* x_p   = (const float*)d_in[0];
  const float* x_np  = (const float*)d_in[1];
  const float* y     = (const float*)d_in[2];
  const int* ei_p    = (const int*)d_in[3];   // int inputs arrive as int32
  const int* ei_np   = (const int*)d_in[4];
  const float* W_gcn = (const float*)d_in[5];
  const float* b_gcn = (const float*)d_in[6];
  const float* W1    = (const float*)d_in[7];
  const float* b1    = (const float*)d_in[8];
  const float* W2    = (const float*)d_in[9];
  const float* b2    = (const float*)d_in[10];
  float* out         = (float*)d_out;

  char* p = (char*)d_ws;
  auto alloc = [&](size_t bytes) -> void* {
    void* r = (void*)p;
    p += (bytes + 255) & ~(size_t)255;
    return r;
  };
  __hip_bfloat16* Ga = (__hip_bfloat16*)alloc((size_t)N_TOT * C_DIM * 2);  // G ping
  __hip_bfloat16* Gb = (__hip_bfloat16*)alloc((size_t)N_TOT * C_DIM * 2);  // G pong
  unsigned* srcs  = (unsigned*)alloc((size_t)(ESZ + EPAD) * 4);  // CSR srcs
  float* norms    = (float*)alloc((size_t)(ESZ + EPAD) * 4);     // CSR norms
  int*   ptr      = (int*)alloc((size_t)(N_TOT + 1) * 4);
  float* dinv     = (float*)alloc((size_t)N_TOT * 4);
  int*   cnt      = (int*)alloc((size_t)N_TOT * 4);
  int*   fill     = (int*)alloc((size_t)N_TOT * 4);
  float* ca       = (float*)alloc((size_t)N_TOT * 4);            // c ping
  float* cb       = (float*)alloc((size_t)N_TOT * 4);            // c pong
  float* Vt_all   = (float*)alloc((size_t)WALK * C_DIM * C_DIM * 4);
  float* dvec_all = (float*)alloc((size_t)WALK * C_DIM * 4);
  float* trG      = (float*)alloc((size_t)WALK * NTR * 4);
  float* ctr      = (float*)alloc((size_t)WALK * NTR * 4);
  int*   bflag    = (int*)alloc(4);

  // --- precompute ---
  init_kernel<<<(N_TOT + 255) / 256, 256, 0, stream>>>(cnt, trG, ctr, ca, bflag,
                                                       srcs, norms);
  count_kernel<<<(E_TOT + 255) / 256, 256, 0, stream>>>(ei_p, ei_np, cnt);
  scan_kernel<<<1, 1024, 0, stream>>>(cnt, ptr);
  dinv_kernel<<<(N_TOT + 255) / 256, 256, 0, stream>>>(cnt, ptr, dinv, fill,
                                                       srcs, norms);
  fill_kernel<<<(E_TOT + 255) / 256, 256, 0, stream>>>(ei_p, ei_np, ptr, fill,
                                                       dinv, srcs, norms);
  {
    const int NT8 = N_TOT * C_DIM / 8;
    concat_kernel<<<(NT8 + 255) / 256, 256, 0, stream>>>(x_p, x_np, Ga);
  }
  wpow_all_kernel<<<C_DIM + 1, C_DIM, 0, stream>>>(W_gcn, Vt_all, dvec_all,
                                                   b_gcn, bflag);

  // --- 7 walk steps ---
  __hip_bfloat16 *Gcur = Ga, *Gnext = Gb;
  float *ccur = ca, *cnext = cb;
  for (int st = 0; st < WALK; ++st) {
    const int notlast = (st < WALK - 1) ? 1 : 0;
    step_kernel<<<N_TOT / 64, 256, 0, stream>>>(Gcur, Gnext, ptr, srcs, norms,
                                                ccur, cnext,
                                                Vt_all + (size_t)st * C_DIM * C_DIM,
                                                dvec_all + (size_t)st * C_DIM,
                                                trG, ctr, bflag, st, notlast);
    { __hip_bfloat16* t = Gcur; Gcur = Gnext; Gnext = t; }
    { float* t = ccur; ccur = cnext; cnext = t; }
  }

  // --- standardize + MLP + sigmoid ---
  final_kernel<<<1, B_SZ, 0, stream>>>(trG, ctr, y, W1, b1, W2, b2, out);
}

// Round 12
// 408.957 us; speedup vs baseline: 3.3824x; 1.1646x over previous
//
#include <hip/hip_runtime.h>
#include <hip/hip_bf16.h>
#include <math.h>

namespace {

constexpr int C_DIM  = 128;
constexpr int B_SZ   = 256;
constexpr int NP_OFF = 32768;         // np-graph node-id offset
constexpr int N_TOT  = 32896;         // 32768 + 128 combined rows
constexpr int E_P    = 524288;
constexpr int E_NP   = 2048;
constexpr int E_TOT  = E_P + E_NP;
constexpr int WALK   = 7;
constexpr int NTR    = 257;           // 256 p-block traces + 1 np trace
constexpr int ELLW   = 64;            // fixed metadata stride per node

// Algebra: H_t = A^t H0 W^t + sum_{k<t} (A^k 1)(b^T W^k); only traces needed:
//   trace_t[b] = <G_t[b-rows], (W^t)^T>_F + bias terms (skipped when b==0).
// G_t = A^t H0 propagated sparsely.
//
// R12: R11's 4-node/quarter step (16 row-gathers in flight, chain-latency
// lever confirmed twice) + scan ELIMINATED: fixed-stride-64 ELL metadata
// (self at slot 0; slots >= deg left UNINITIALIZED -- consume masks weights
// by j<deg via select and clamps garbage srcs, so no memset needed). R8
// proved metadata size/padding is a non-factor (gather misses dominate).
// final_kernel reductions moved to wave shuffles (4 syncs/step vs ~20).

__device__ __forceinline__ float bflo(unsigned int w) { return __uint_as_float(w << 16); }
__device__ __forceinline__ float bfhi(unsigned int w) { return __uint_as_float(w & 0xffff0000u); }

// ---------------- precompute ----------------

__global__ void init_kernel(int* __restrict__ cnt, float* __restrict__ trG,
                            float* __restrict__ ctr, float* __restrict__ c0,
                            int* __restrict__ bflag) {
  int i = blockIdx.x * blockDim.x + threadIdx.x;
  if (i < N_TOT) { cnt[i] = 0; c0[i] = 1.0f; }
  if (i < WALK * NTR) { trG[i] = 0.0f; ctr[i] = 0.0f; }
  if (i == 0) *bflag = 0;
}

// NOTE: harness delivers integer inputs as int32
__global__ void count_kernel(const int* __restrict__ ei_p,
                             const int* __restrict__ ei_np,
                             int* __restrict__ cnt) {
  int e = blockIdx.x * blockDim.x + threadIdx.x;
  if (e < E_P) {
    int d = ei_p[E_P + e];
    atomicAdd(&cnt[d], 1);
  } else if (e < E_TOT) {
    int i = e - E_P;
    int d = ei_np[E_NP + i] + NP_OFF;
    atomicAdd(&cnt[d], 1);
  }
}

// dinv + self-loop edge at slot node*ELLW
__global__ void dinv_kernel(const int* __restrict__ cnt,
                            float* __restrict__ dinv, int* __restrict__ fill,
                            unsigned* __restrict__ srcs, float* __restrict__ norms) {
  int i = blockIdx.x * blockDim.x + threadIdx.x;
  if (i < N_TOT) {
    float di = rsqrtf((float)cnt[i] + 1.0f);  // +1 self loop
    dinv[i] = di;
    fill[i] = 0;
    size_t p = (size_t)i * ELLW;
    srcs[p] = (unsigned)i;
    norms[p] = di * di;
  }
}

__global__ void fill_kernel(const int* __restrict__ ei_p,
                            const int* __restrict__ ei_np,
                            int* __restrict__ fill,
                            const float* __restrict__ dinv,
                            unsigned* __restrict__ srcs, float* __restrict__ norms) {
  int e = blockIdx.x * blockDim.x + threadIdx.x;
  int s, d;
  if (e < E_P) {
    s = ei_p[e];
    d = ei_p[E_P + e];
  } else if (e < E_TOT) {
    int i = e - E_P;
    s = ei_np[i] + NP_OFF;
    d = ei_np[E_NP + i] + NP_OFF;
  } else {
    return;
  }
  int k = atomicAdd(&fill[d], 1);              // 0-based among real edges
  if (k < ELLW - 1) {                          // cap: self + 63 real = 64 slots
    size_t pos = (size_t)d * ELLW + 1 + k;
    srcs[pos] = (unsigned)s;
    norms[pos] = dinv[s] * dinv[d];
  }
}

// G0 = round_bf16([x_p ; x_np]); thread handles 8 floats -> one 16B bf16 store
__global__ void concat_kernel(const float* __restrict__ x_p,
                              const float* __restrict__ x_np,
                              __hip_bfloat16* __restrict__ hb) {
  int i = blockIdx.x * blockDim.x + threadIdx.x;  // 8-elem chunk index
  const int NP8 = NP_OFF * C_DIM / 8;
  const int NT8 = N_TOT * C_DIM / 8;
  if (i >= NT8) return;
  const float* src = (i < NP8) ? (x_p + (size_t)i * 8)
                               : (x_np + (size_t)(i - NP8) * 8);
  union { __hip_bfloat16 h[8]; uint4 u; } pk;
#pragma unroll
  for (int j = 0; j < 8; ++j) pk.h[j] = __float2bfloat16(src[j]);
  ((uint4*)hb)[i] = pk.u;
}

// ---------------- all W powers in ONE kernel ----------------
__global__ __launch_bounds__(128) void wpow_all_kernel(
    const float* __restrict__ W, float* __restrict__ Vt_all,
    float* __restrict__ dvec_all, const float* __restrict__ bg,
    int* __restrict__ bflag) {
  __shared__ float cur[C_DIM];
  const int i = blockIdx.x;
  const int j = threadIdx.x;
  if (i < C_DIM) {
    float u = W[i * C_DIM + j];                 // U_1 row i
    Vt_all[0 * C_DIM * C_DIM + j * C_DIM + i] = u;
    for (int st = 1; st < WALK; ++st) {
      cur[j] = u;
      __syncthreads();
      float nu = 0.0f;
      for (int k = 0; k < C_DIM; ++k) nu += cur[k] * W[k * C_DIM + j];
      __syncthreads();
      u = nu;
      Vt_all[st * C_DIM * C_DIM + j * C_DIM + i] = u;
    }
  } else {
    float d = bg[j];
    if (d != 0.0f) atomicOr(bflag, 1);
    dvec_all[0 * C_DIM + j] = d;
    for (int st = 1; st < WALK; ++st) {
      cur[j] = d;
      __syncthreads();
      float nd = 0.0f;
      for (int k = 0; k < C_DIM; ++k) nd += cur[k] * W[k * C_DIM + j];
      __syncthreads();
      d = nd;
      dvec_all[st * C_DIM + j] = d;
    }
  }
}

// ---------------- fused walk step: 4 nodes per quarter, interleaved ----------
__global__ __launch_bounds__(256) void step_kernel(
    const __hip_bfloat16* __restrict__ Gin,
    __hip_bfloat16* __restrict__ Gout,
    const int* __restrict__ cnt,
    const unsigned* __restrict__ srcs,
    const float* __restrict__ norms,
    const float* __restrict__ cin,
    float* __restrict__ cout,
    const float* __restrict__ Vt,    // (W^{st+1})^T, row-major [128][128]
    const float* __restrict__ dvec,  // d_st = b^T W^st
    float* __restrict__ trG,
    float* __restrict__ ctr,
    const int* __restrict__ bflag,
    int st, int notlast) {
  const int lane = threadIdx.x & 63;
  const int wv   = threadIdx.x >> 6;
  const int q    = lane >> 4;   // quarter
  const int c8   = lane & 15;   // 8-channel (16B) group within row
  const int base = (blockIdx.x * 4 + wv) * 16;      // 16 nodes per wave
  const int n0   = base + 4 * q;                    // N_TOT = 64*514 exact
  const int n1   = n0 + 1;
  const int n2   = n0 + 2;
  const int n3   = n0 + 3;
  const int qb   = q << 4;

  int d0 = cnt[n0] + 1; if (d0 > ELLW) d0 = ELLW;
  int d1 = cnt[n1] + 1; if (d1 > ELLW) d1 = ELLW;
  int d2 = cnt[n2] + 1; if (d2 > ELLW) d2 = ELLW;
  int d3 = cnt[n3] + 1; if (d3 > ELLW) d3 = ELLW;
  int dmax = d0 > d1 ? d0 : d1;
  dmax = dmax > d2 ? dmax : d2;
  dmax = dmax > d3 ? dmax : d3;

  const unsigned* S0 = srcs + (size_t)n0 * ELLW;  const float* F0 = norms + (size_t)n0 * ELLW;
  const unsigned* S1 = srcs + (size_t)n1 * ELLW;  const float* F1 = norms + (size_t)n1 * ELLW;
  const unsigned* S2 = srcs + (size_t)n2 * ELLW;  const float* F2 = norms + (size_t)n2 * ELLW;
  const unsigned* S3 = srcs + (size_t)n3 * ELLW;  const float* F3 = norms + (size_t)n3 * ELLW;

  const uint4* __restrict__ G16 = (const uint4*)Gin;

  float acc0[8], acc1[8], acc2[8], acc3[8];
#pragma unroll
  for (int i = 0; i < 8; ++i) { acc0[i] = 0.0f; acc1[i] = 0.0f;
                                acc2[i] = 0.0f; acc3[i] = 0.0f; }

  // Issue 4 gathers for node K this round. Letter suffixes (a..d) keep the
  // pasted name away from `.member` (pp-number pitfall: `0.x` is one token).
#define LOADN(K, SX, NX, DK)                                                   \
    unsigned x##K##a = __shfl(SX, qb + rr * 4 + 0);                            \
    unsigned x##K##b = __shfl(SX, qb + rr * 4 + 1);                            \
    unsigned x##K##c = __shfl(SX, qb + rr * 4 + 2);                            \
    unsigned x##K##d = __shfl(SX, qb + rr * 4 + 3);                            \
    float w##K##a = __shfl(NX, qb + rr * 4 + 0);                               \
    float w##K##b = __shfl(NX, qb + rr * 4 + 1);                               \
    float w##K##c = __shfl(NX, qb + rr * 4 + 2);                               \
    float w##K##d = __shfl(NX, qb + rr * 4 + 3);                               \
    w##K##a = (j0 + 0 < DK) ? w##K##a : 0.0f;                                  \
    w##K##b = (j0 + 1 < DK) ? w##K##b : 0.0f;                                  \
    w##K##c = (j0 + 2 < DK) ? w##K##c : 0.0f;                                  \
    w##K##d = (j0 + 3 < DK) ? w##K##d : 0.0f;                                  \
    x##K##a = x##K##a < N_TOT ? x##K##a : 0u;                                  \
    x##K##b = x##K##b < N_TOT ? x##K##b : 0u;                                  \
    x##K##c = x##K##c < N_TOT ? x##K##c : 0u;                                  \
    x##K##d = x##K##d < N_TOT ? x##K##d : 0u;                                  \
    uint4 g##K##a = G16[(size_t)x##K##a * 16 + c8];                            \
    uint4 g##K##b = G16[(size_t)x##K##b * 16 + c8];                            \
    uint4 g##K##c = G16[(size_t)x##K##c * 16 + c8];                            \
    uint4 g##K##d = G16[(size_t)x##K##d * 16 + c8];

#define CONSN(K, ACC)                                                          \
    ACC[0] += w##K##a * bflo(g##K##a.x) + w##K##b * bflo(g##K##b.x)            \
            + w##K##c * bflo(g##K##c.x) + w##K##d * bflo(g##K##d.x);           \
    ACC[1] += w##K##a * bfhi(g##K##a.x) + w##K##b * bfhi(g##K##b.x)            \
            + w##K##c * bfhi(g##K##c.x) + w##K##d * bfhi(g##K##d.x);           \
    ACC[2] += w##K##a * bflo(g##K##a.y) + w##K##b * bflo(g##K##b.y)            \
            + w##K##c * bflo(g##K##c.y) + w##K##d * bflo(g##K##d.y);           \
    ACC[3] += w##K##a * bfhi(g##K##a.y) + w##K##b * bfhi(g##K##b.y)            \
            + w##K##c * bfhi(g##K##c.y) + w##K##d * bfhi(g##K##d.y);           \
    ACC[4] += w##K##a * bflo(g##K##a.z) + w##K##b * bflo(g##K##b.z)            \
            + w##K##c * bflo(g##K##c.z) + w##K##d * bflo(g##K##d.z);           \
    ACC[5] += w##K##a * bfhi(g##K##a.z) + w##K##b * bfhi(g##K##b.z)            \
            + w##K##c * bfhi(g##K##c.z) + w##K##d * bfhi(g##K##d.z);           \
    ACC[6] += w##K##a * bflo(g##K##a.w) + w##K##b * bflo(g##K##b.w)            \
            + w##K##c * bflo(g##K##c.w) + w##K##d * bflo(g##K##d.w);           \
    ACC[7] += w##K##a * bfhi(g##K##a.w) + w##K##b * bfhi(g##K##b.w)            \
            + w##K##c * bfhi(g##K##c.w) + w##K##d * bfhi(g##K##d.w);

#define GROUP4(SX0, NX0, SX1, NX1, SX2, NX2, SX3, NX3, RG)                     \
  {                                                                            \
    for (int rr = 0; rr < 4; ++rr) {                                           \
      const int j0 = (RG) * 16 + rr * 4;                                       \
      if (j0 >= dmax) break;                                                   \
      LOADN(0, SX0, NX0, d0)                                                   \
      LOADN(1, SX1, NX1, d1)                                                   \
      LOADN(2, SX2, NX2, d2)                                                   \
      LOADN(3, SX3, NX3, d3)                                                   \
      CONSN(0, acc0)                                                           \
      CONSN(1, acc1)                                                           \
      CONSN(2, acc2)                                                           \
      CONSN(3, acc3)                                                           \
    }                                                                          \
  }

  // banks A,B upfront (covers deg <= 32, the common case); C,D lazy.
  {
    unsigned sA0 = S0[c8], sA1 = S1[c8], sA2 = S2[c8], sA3 = S3[c8];
    float    nA0 = F0[c8], nA1 = F1[c8], nA2 = F2[c8], nA3 = F3[c8];
    unsigned sB0 = S0[16 + c8], sB1 = S1[16 + c8], sB2 = S2[16 + c8], sB3 = S3[16 + c8];
    float    nB0 = F0[16 + c8], nB1 = F1[16 + c8], nB2 = F2[16 + c8], nB3 = F3[16 + c8];
    GROUP4(sA0, nA0, sA1, nA1, sA2, nA2, sA3, nA3, 0)
    if (16 < dmax) {
      GROUP4(sB0, nB0, sB1, nB1, sB2, nB2, sB3, nB3, 1)
    }
  }
  if (32 < dmax) {
    unsigned sC0 = S0[32 + c8], sC1 = S1[32 + c8], sC2 = S2[32 + c8], sC3 = S3[32 + c8];
    float    nC0 = F0[32 + c8], nC1 = F1[32 + c8], nC2 = F2[32 + c8], nC3 = F3[32 + c8];
    GROUP4(sC0, nC0, sC1, nC1, sC2, nC2, sC3, nC3, 2)
    if (48 < dmax) {
      unsigned sD0 = S0[48 + c8], sD1 = S1[48 + c8], sD2 = S2[48 + c8], sD3 = S3[48 + c8];
      float    nD0 = F0[48 + c8], nD1 = F1[48 + c8], nD2 = F2[48 + c8], nD3 = F3[48 + c8];
      GROUP4(sD0, nD0, sD1, nD1, sD2, nD2, sD3, nD3, 3)
    }
  }
#undef GROUP4
#undef CONSN
#undef LOADN

  if (notlast) {
    union { __hip_bfloat16 h[8]; uint4 u; } pk0, pk1, pk2, pk3;
#pragma unroll
    for (int i = 0; i < 8; ++i) { pk0.h[i] = __float2bfloat16(acc0[i]);
                                  pk1.h[i] = __float2bfloat16(acc1[i]);
                                  pk2.h[i] = __float2bfloat16(acc2[i]);
                                  pk3.h[i] = __float2bfloat16(acc3[i]); }
    ((uint4*)Gout)[(size_t)n0 * 16 + c8] = pk0.u;
    ((uint4*)Gout)[(size_t)n1 * 16 + c8] = pk1.u;
    ((uint4*)Gout)[(size_t)n2 * 16 + c8] = pk2.u;
    ((uint4*)Gout)[(size_t)n3 * 16 + c8] = pk3.u;
  }

  // traces: dot(G_new[n], Vt[n&127][:]); n0..n3 share the same 128-block
  const int col0 = n0 & 127, col1 = n1 & 127, col2 = n2 & 127, col3 = n3 & 127;
  const float4* vr0 = (const float4*)(Vt + col0 * C_DIM + c8 * 8);
  const float4* vr1 = (const float4*)(Vt + col1 * C_DIM + c8 * 8);
  const float4* vr2 = (const float4*)(Vt + col2 * C_DIM + c8 * 8);
  const float4* vr3 = (const float4*)(Vt + col3 * C_DIM + c8 * 8);
  const float4 v00 = vr0[0], v01 = vr0[1];
  const float4 v10 = vr1[0], v11 = vr1[1];
  const float4 v20 = vr2[0], v21 = vr2[1];
  const float4 v30 = vr3[0], v31 = vr3[1];
  float pd = acc0[0] * v00.x + acc0[1] * v00.y + acc0[2] * v00.z + acc0[3] * v00.w +
             acc0[4] * v01.x + acc0[5] * v01.y + acc0[6] * v01.z + acc0[7] * v01.w;
  pd      += acc1[0] * v10.x + acc1[1] * v10.y + acc1[2] * v10.z + acc1[3] * v10.w +
             acc1[4] * v11.x + acc1[5] * v11.y + acc1[6] * v11.z + acc1[7] * v11.w;
  pd      += acc2[0] * v20.x + acc2[1] * v20.y + acc2[2] * v20.z + acc2[3] * v20.w +
             acc2[4] * v21.x + acc2[5] * v21.y + acc2[6] * v21.z + acc2[7] * v21.w;
  pd      += acc3[0] * v30.x + acc3[1] * v30.y + acc3[2] * v30.z + acc3[3] * v30.w +
             acc3[4] * v31.x + acc3[5] * v31.y + acc3[6] * v31.z + acc3[7] * v31.w;
  pd += __shfl_xor(pd, 1);
  pd += __shfl_xor(pd, 2);
  pd += __shfl_xor(pd, 4);
  pd += __shfl_xor(pd, 8);

  const int bnz = *bflag;
  if (c8 == 0) {
    atomicAdd(&trG[st * NTR + (n0 >> 7)], pd);
    if (bnz) {  // exact bias path (unused when b_gcn == 0)
      float cs0 = cin[n0], cn0 = 0.0f;
      for (int e = 0; e < d0; ++e) cn0 += F0[e] * cin[S0[e]];
      float cs1 = cin[n1], cn1 = 0.0f;
      for (int e = 0; e < d1; ++e) cn1 += F1[e] * cin[S1[e]];
      float cs2 = cin[n2], cn2 = 0.0f;
      for (int e = 0; e < d2; ++e) cn2 += F2[e] * cin[S2[e]];
      float cs3 = cin[n3], cn3 = 0.0f;
      for (int e = 0; e < d3; ++e) cn3 += F3[e] * cin[S3[e]];
      if (notlast) { cout[n0] = cn0; cout[n1] = cn1;
                     cout[n2] = cn2; cout[n3] = cn3; }
      atomicAdd(&ctr[st * NTR + (n0 >> 7)],
                cs0 * dvec[col0] + cs1 * dvec[col1] +
                cs2 * dvec[col2] + cs3 * dvec[col3]);
    }
  }
}

// ---------------- epilogue ----------------
// trace_t = trG[t] + prefix_sum_{k<=t} ctr[k]; wave-shuffle reductions.
__global__ __launch_bounds__(256) void final_kernel(const float* __restrict__ trG,
                                                    const float* __restrict__ ctr,
                                                    const float* __restrict__ y,
                                                    const float* __restrict__ W1,
                                                    const float* __restrict__ b1,
                                                    const float* __restrict__ W2,
                                                    const float* __restrict__ b2,
                                                    float* __restrict__ out) {
  __shared__ float part[4];
  const int b  = threadIdx.x;
  const int ln = b & 63;
  const int wv = b >> 6;
  const float sgn = (y[b] - 0.5f) * 2.0f;
  float runb = 0.0f, runn = 0.0f;
  float vals[WALK];
#pragma unroll
  for (int t = 0; t < WALK; ++t) {
    runb += ctr[t * NTR + b];
    runn += ctr[t * NTR + 256];
    vals[t] = ((trG[t * NTR + b] + runb) - (trG[t * NTR + 256] + runn)) * sgn;
  }

  for (int t = 0; t < WALK; ++t) {
    float v = vals[t];
    v += __shfl_xor(v, 1);  v += __shfl_xor(v, 2);  v += __shfl_xor(v, 4);
    v += __shfl_xor(v, 8);  v += __shfl_xor(v, 16); v += __shfl_xor(v, 32);
    if (ln == 0) part[wv] = v;
    __syncthreads();
    float mean = (part[0] + part[1] + part[2] + part[3]) * (1.0f / 256.0f);
    __syncthreads();
    float d = vals[t] - mean;
    v = d * d;
    v += __shfl_xor(v, 1);  v += __shfl_xor(v, 2);  v += __shfl_xor(v, 4);
    v += __shfl_xor(v, 8);  v += __shfl_xor(v, 16); v += __shfl_xor(v, 32);
    if (ln == 0) part[wv] = v;
    __syncthreads();
    float stdv = sqrtf((part[0] + part[1] + part[2] + part[3]) * (1.0f / 255.0f));
    __syncthreads();
    vals[t] = d / stdv;
  }

  float o = b2[0];
#pragma unroll
  for (int j = 0; j < 15; ++j) {
    float a = b1[j];
#pragma unroll
    for (int t = 0; t < WALK; ++t) a += vals[t] * W1[t * 15 + j];
    o += fmaxf(a, 0.0f) * W2[j];
  }
  out[b] = 1.0f / (1.0f + expf(-o));
}

}  // namespace

extern "C" void kernel_launch(void* const* d_in, const int* in_sizes, int n_in,
                              void* d_out, int out_size, void* d_ws, size_t ws_size,
                              hipStream_t stream) {
  const float* x_p   = (const float*)d_in[0];
  const float* x_np  = (const float*)d_in[1];
  const float* y     = (const float*)d_in[2];
  const int* ei_p    = (const int*)d_in[3];   // int inputs arrive as int32
  const int* ei_np   = (const int*)d_in[4];
  const float* W_gcn = (const float*)d_in[5];
  const float* b_gcn = (const float*)d_in[6];
  const float* W1    = (const float*)d_in[7];
  const float* b1    = (const float*)d_in[8];
  const float* W2    = (const float*)d_in[9];
  const float* b2    = (const float*)d_in[10];
  float* out         = (float*)d_out;

  char* p = (char*)d_ws;
  auto alloc = [&](size_t bytes) -> void* {
    void* r = (void*)p;
    p += (bytes + 255) & ~(size_t)255;
    return r;
  };
  __hip_bfloat16* Ga = (__hip_bfloat16*)alloc((size_t)N_TOT * C_DIM * 2);  // G ping
  __hip_bfloat16* Gb = (__hip_bfloat16*)alloc((size_t)N_TOT * C_DIM * 2);  // G pong
  unsigned* srcs  = (unsigned*)alloc((size_t)N_TOT * ELLW * 4);  // ELL srcs
  float* norms    = (float*)alloc((size_t)N_TOT * ELLW * 4);     // ELL norms
  float* dinv     = (float*)alloc((size_t)N_TOT * 4);
  int*   cnt      = (int*)alloc((size_t)N_TOT * 4);
  int*   fill     = (int*)alloc((size_t)N_TOT * 4);
  float* ca       = (float*)alloc((size_t)N_TOT * 4);            // c ping
  float* cb       = (float*)alloc((size_t)N_TOT * 4);            // c pong
  float* Vt_all   = (float*)alloc((size_t)WALK * C_DIM * C_DIM * 4);
  float* dvec_all = (float*)alloc((size_t)WALK * C_DIM * 4);
  float* trG      = (float*)alloc((size_t)WALK * NTR * 4);
  float* ctr      = (float*)alloc((size_t)WALK * NTR * 4);
  int*   bflag    = (int*)alloc(4);

  // --- precompute (no scan; slots >= deg never consumed, no memset) ---
  init_kernel<<<(N_TOT + 255) / 256, 256, 0, stream>>>(cnt, trG, ctr, ca, bflag);
  count_kernel<<<(E_TOT + 255) / 256, 256, 0, stream>>>(ei_p, ei_np, cnt);
  dinv_kernel<<<(N_TOT + 255) / 256, 256, 0, stream>>>(cnt, dinv, fill,
                                                       srcs, norms);
  fill_kernel<<<(E_TOT + 255) / 256, 256, 0, stream>>>(ei_p, ei_np, fill,
                                                       dinv, srcs, norms);
  {
    const int NT8 = N_TOT * C_DIM / 8;
    concat_kernel<<<(NT8 + 255) / 256, 256, 0, stream>>>(x_p, x_np, Ga);
  }
  wpow_all_kernel<<<C_DIM + 1, C_DIM, 0, stream>>>(W_gcn, Vt_all, dvec_all,
                                                   b_gcn, bflag);

  // --- 7 walk steps ---
  __hip_bfloat16 *Gcur = Ga, *Gnext = Gb;
  float *ccur = ca, *cnext = cb;
  for (int st = 0; st < WALK; ++st) {
    const int notlast = (st < WALK - 1) ? 1 : 0;
    step_kernel<<<N_TOT / 64, 256, 0, stream>>>(Gcur, Gnext, cnt, srcs, norms,
                                                ccur, cnext,
                                                Vt_all + (size_t)st * C_DIM * C_DIM,
                                                dvec_all + (size_t)st * C_DIM,
                                                trG, ctr, bflag, st, notlast);
    { __hip_bfloat16* t = Gcur; Gcur = Gnext; Gnext = t; }
    { float* t = ccur; ccur = cnext; cnext = t; }
  }

  // --- standardize + MLP + sigmoid ---
  final_kernel<<<1, B_SZ, 0, stream>>>(trG, ctr, y, W1, b1, W2, b2, out);
}